// Round 8
// baseline (973.723 us; speedup 1.0000x reference)
//
#include <hip/hip_runtime.h>

// Transformer layer, bf16 MFMA compute, fp32 I/O.
// B=2 T=2048 E=2048 H=16 DH=128 FFN=8192. Needs ~235MB workspace.

#define T_SEQ 2048
#define E_DIM 2048
#define N_HEAD 16
#define D_HEAD 128
#define FFN_DIM 8192
#define M_ROWS 4096  // B*T
#define QS (3 * E_DIM)  // fused QKV row stride

typedef unsigned short u16;
typedef short short8 __attribute__((ext_vector_type(8)));
typedef float f32x4 __attribute__((ext_vector_type(4)));

#define DEV __device__ __forceinline__

DEV u16 f2bf(float f) {
  unsigned u = __float_as_uint(f);
  u += 0x7fffu + ((u >> 16) & 1u);
  return (u16)(u >> 16);
}
DEV float bf2f(u16 h) { return __uint_as_float(((unsigned)h) << 16); }

DEV void async16(void* lds, const void* g) {
  __builtin_amdgcn_global_load_lds((const __attribute__((address_space(1))) void*)g,
                                   (__attribute__((address_space(3))) void*)lds, 16, 0, 0);
}

// ---------------- LayerNorm: fp32 [rows][E] -> bf16 -----------------
__global__ __launch_bounds__(256) void ln_kernel(const float* __restrict__ x,
                                                 const float* __restrict__ gw,
                                                 const float* __restrict__ bw,
                                                 u16* __restrict__ out) {
  int row = blockIdx.x;
  int t = threadIdx.x;
  const float4* xr = (const float4*)(x + (size_t)row * E_DIM);
  float4 a = xr[t], c = xr[t + 256];
  float s = a.x + a.y + a.z + a.w + c.x + c.y + c.z + c.w;
  float q = a.x * a.x + a.y * a.y + a.z * a.z + a.w * a.w +
            c.x * c.x + c.y * c.y + c.z * c.z + c.w * c.w;
  for (int off = 32; off > 0; off >>= 1) {
    s += __shfl_down(s, off);
    q += __shfl_down(q, off);
  }
  __shared__ float red[8];
  if ((t & 63) == 0) { red[(t >> 6) * 2] = s; red[(t >> 6) * 2 + 1] = q; }
  __syncthreads();
  s = red[0] + red[2] + red[4] + red[6];
  q = red[1] + red[3] + red[5] + red[7];
  float mu = s * (1.f / E_DIM);
  float rs = rsqrtf(q * (1.f / E_DIM) - mu * mu + 1e-5f);
  const float4* g4 = (const float4*)gw;
  const float4* b4 = (const float4*)bw;
  float4 g0 = g4[t], g1v = g4[t + 256], e0 = b4[t], e1 = b4[t + 256];
  ushort4 o0, o1;
  o0.x = f2bf((a.x - mu) * rs * g0.x + e0.x);
  o0.y = f2bf((a.y - mu) * rs * g0.y + e0.y);
  o0.z = f2bf((a.z - mu) * rs * g0.z + e0.z);
  o0.w = f2bf((a.w - mu) * rs * g0.w + e0.w);
  o1.x = f2bf((c.x - mu) * rs * g1v.x + e1.x);
  o1.y = f2bf((c.y - mu) * rs * g1v.y + e1.y);
  o1.z = f2bf((c.z - mu) * rs * g1v.z + e1.z);
  o1.w = f2bf((c.w - mu) * rs * g1v.w + e1.w);
  ((ushort4*)(out + (size_t)row * E_DIM))[t] = o0;
  ((ushort4*)(out + (size_t)row * E_DIM))[t + 256] = o1;
}

// ------- convert+transpose: fp32 W[K][N] -> bf16 WT[N][K] -----------
__global__ __launch_bounds__(256) void cvt_t_kernel(const float* __restrict__ W,
                                                    u16* __restrict__ WT,
                                                    int Kd, int Nd) {
  __shared__ float tile[32][33];
  int tx = threadIdx.x, ty = threadIdx.y;
  int n0 = blockIdx.x * 32, k0 = blockIdx.y * 32;
#pragma unroll
  for (int i = 0; i < 4; i++)
    tile[ty + i * 8][tx] = W[(size_t)(k0 + ty + i * 8) * Nd + n0 + tx];
  __syncthreads();
#pragma unroll
  for (int i = 0; i < 4; i++)
    WT[(size_t)(n0 + ty + i * 8) * Kd + k0 + tx] = f2bf(tile[tx][ty + i * 8]);
}

// -- transpose V from fused QKV: bf16 [B*T][QS] col 4096+ -> [B][E][T]
__global__ __launch_bounds__(256) void transpose_v_kernel(const u16* __restrict__ qkv,
                                                          u16* __restrict__ vt) {
  __shared__ u16 tile[32][33];
  int tx = threadIdx.x, ty = threadIdx.y;
  int b = blockIdx.z;
  int t0 = blockIdx.x * 32, e0 = blockIdx.y * 32;
#pragma unroll
  for (int i = 0; i < 4; i++)
    tile[ty + i * 8][tx] =
        qkv[(size_t)(b * T_SEQ + t0 + ty + i * 8) * QS + 2 * E_DIM + e0 + tx];
  __syncthreads();
#pragma unroll
  for (int i = 0; i < 4; i++)
    vt[((size_t)b * E_DIM + e0 + ty + i * 8) * T_SEQ + t0 + tx] = tile[tx][ty + i * 8];
}

// ==== GEMM 128x256xBK64, 4-phase + register READ-AHEAD pipeline =====
// C[M][N] = A[M][K] * BT[N][K]^T.  512 thr = 8 waves (2Mx4N), wave
// tile 64x64.  Paired-row LDS (round-5-proven 0-conflict), units
// [db][ks][128|256 rows][32].  4 merged phases per 2 K-tiles; each
// phase: {ds_read NEXT phase's frags into alternate reg set; stage
// 1 A-unit + 1 B-unit; setprio(1); 16 MFMA on CURRENT reg set;
// setprio(0); sched_barrier(0); vmcnt(3); s_barrier}.  lgkm waits are
// compiler-inserted counted waits (reads are plain C++ loads), so the
// ds_reads of phase P+1 overlap phase P's MFMA -- removes the
// read/MFMA CU-level serialization that capped MfmaUtil at 29%.
// Hazard ledger: every slot's last read completes (lgkm before the
// end-of-phase barrier) >=1 barrier before restaging; every read-issue
// is >=1 vmcnt(3)-guarded barrier after its staging.
// Stagger: P0 stages db1ks1(tb) / P1 db0ks0(t2) / P2 db0ks1(t2) /
// P3 db1ks0(t3).  Reads: P0->db0ks1, P1->db1ks0, P2->db1ks1,
// P3->db0ks0(t2).  Last iter: skip staging P1-P3, drain vmcnt(0).
// MODE 0: bf16 C.  MODE 1: Cout(f32)=Extra(f32)+acc.
// MODE 2: Cout(bf16)=silu(Extra bf16)*acc.
template <int MODE>
__global__ __launch_bounds__(512, 1) void gemm4p(const u16* __restrict__ A,
                                                 const u16* __restrict__ BT,
                                                 void* __restrict__ Cout,
                                                 const void* __restrict__ Extra,
                                                 int N, int K, int colMajorXcd) {
  __shared__ u16 Abuf[4 * 4096];   // 32 KB
  __shared__ u16 Bbuf[4 * 8192];   // 64 KB
  const int t = threadIdx.x;
  const int w = t >> 6, l = t & 63, g = l >> 4, lq = l & 15;
  const int wm = w >> 2, wn = w & 3;

  // T1: bijective XCD swizzle (all grids have nwg % 8 == 0)
  const int gx = gridDim.x, gy = gridDim.y;
  const int nwg = gx * gy;
  int lin = colMajorXcd ? (blockIdx.x * gy + blockIdx.y)
                        : (blockIdx.y * gx + blockIdx.x);
  const int qq = nwg >> 3;
  int wg = (lin & 7) * qq + (lin >> 3);
  int bx, by;
  if (colMajorXcd) { bx = wg / gy; by = wg - bx * gy; }
  else             { by = wg / gx; bx = wg - by * gx; }
  const size_t bm = (size_t)by * 128, bn = (size_t)bx * 256;

  // staging lane constants (paired-row)
  const int srcrow = ((l >> 3) << 1) | (l & 1);
  const int csrc = ((((l >> 1) & 3) ^ ((l >> 3) & 3)) << 3);
  const u16* aSrc = A + (bm + w * 16 + srcrow) * (size_t)K + csrc;
  const u16* bSrc = BT + (bn + w * 16 + srcrow) * (size_t)K + csrc;
  const int rdoff = (((lq & 1) + 2 * (g ^ ((lq >> 1) & 3))) << 3);

#define STA(DB, KS, TILE)                                                     \
  async16(Abuf + (DB)*8192 + (KS)*4096 + w * 512,                             \
          aSrc + (size_t)(TILE)*64 + (KS)*32);
#define STB(DB, KS, TILE)                                                     \
  {                                                                           \
    u16* Bd = Bbuf + (DB)*16384 + (KS)*8192 + w * 512;                        \
    const u16* bs_ = bSrc + (size_t)(TILE)*64 + (KS)*32;                      \
    async16(Bd, bs_);                                                         \
    async16(Bd + 4096, bs_ + (size_t)128 * K);                                \
  }
#define RD_A(DST, DB, KS)                                                     \
  _Pragma("unroll") for (int m2 = 0; m2 < 4; ++m2)                            \
      DST[m2] = *(const short8*)(Abuf + (DB)*8192 + (KS)*4096 +               \
                                 (wm * 32 + m2 * 8 + (lq >> 1)) * 64 + rdoff);
#define RD_B(DST, DB, KS)                                                     \
  _Pragma("unroll") for (int nn = 0; nn < 4; ++nn)                            \
      DST[nn] = *(const short8*)(Bbuf + (DB)*16384 + (KS)*8192 +              \
                                 (wn * 32 + nn * 8 + (lq >> 1)) * 64 + rdoff);
#define MMA(AF, BF)                                                           \
  _Pragma("unroll") for (int m2 = 0; m2 < 4; ++m2)                            \
      _Pragma("unroll") for (int nn = 0; nn < 4; ++nn)                        \
          acc[m2][nn] = __builtin_amdgcn_mfma_f32_16x16x32_bf16(              \
              AF[m2], BF[nn], acc[m2][nn], 0, 0, 0);
#define ENDPH(VN_STR)                                                         \
  __builtin_amdgcn_s_setprio(0);                                              \
  __builtin_amdgcn_sched_barrier(0);                                          \
  asm volatile("s_waitcnt vmcnt(" VN_STR ")" ::: "memory");                   \
  asm volatile("s_barrier" ::: "memory");

  const int NT = K >> 6, NI = NT >> 1;
  f32x4 acc[4][4] = {};
  short8 af0[4], bf0[4], af1[4], bf1[4];

  // prologue: stage t0 both halves + t1-ks0 (9 loads/thread)
  STA(0, 0, 0); STB(0, 0, 0);
  STA(0, 1, 0); STB(0, 1, 0);
  STA(1, 0, 1); STB(1, 0, 1);
  asm volatile("s_waitcnt vmcnt(3)" ::: "memory");  // t0 fully resident
  asm volatile("s_barrier" ::: "memory");
  RD_A(af0, 0, 0); RD_B(bf0, 0, 0);

  for (int j = 0; j < NI; ++j) {
    const int tb = 2 * j + 1, t2 = 2 * j + 2, t3 = 2 * j + 3;
    const bool li = (j + 1 == NI);
    // P0: mfma db0ks0 (set0); read set1 <- db0ks1; stage db1ks1 <- tb
    RD_A(af1, 0, 1); RD_B(bf1, 0, 1);
    STA(1, 1, tb); STB(1, 1, tb);
    __builtin_amdgcn_s_setprio(1);
    MMA(af0, bf0);
    ENDPH("3")
    // P1: mfma db0ks1 (set1); read set0 <- db1ks0; stage db0ks0 <- t2
    RD_A(af0, 1, 0); RD_B(bf0, 1, 0);
    if (!li) { STA(0, 0, t2); STB(0, 0, t2); }
    __builtin_amdgcn_s_setprio(1);
    MMA(af1, bf1);
    if (!li) { ENDPH("3") } else { ENDPH("0") }
    // P2: mfma db1ks0 (set0); read set1 <- db1ks1; stage db0ks1 <- t2
    RD_A(af1, 1, 1); RD_B(bf1, 1, 1);
    if (!li) { STA(0, 1, t2); STB(0, 1, t2); }
    __builtin_amdgcn_s_setprio(1);
    MMA(af0, bf0);
    if (!li) { ENDPH("3") } else { ENDPH("0") }
    // P3: mfma db1ks1 (set1); read set0 <- db0ks0(t2); stage db1ks0 <- t3
    if (!li) {
      RD_A(af0, 0, 0); RD_B(bf0, 0, 0);
      STA(1, 0, t3); STB(1, 0, t3);
    }
    __builtin_amdgcn_s_setprio(1);
    MMA(af1, bf1);
    if (!li) { ENDPH("3") } else { __builtin_amdgcn_s_setprio(0); }
  }
#undef STA
#undef STB
#undef RD_A
#undef RD_B
#undef MMA
#undef ENDPH

#pragma unroll
  for (int m = 0; m < 4; m++) {
    size_t row = bm + wm * 64 + m * 16 + 4 * g;
#pragma unroll
    for (int n = 0; n < 4; n++) {
      size_t col = bn + wn * 64 + n * 16 + lq;
#pragma unroll
      for (int r = 0; r < 4; r++) {
        size_t idx = (row + r) * (size_t)N + col;
        if constexpr (MODE == 0) {
          ((u16*)Cout)[idx] = f2bf(acc[m][n][r]);
        } else if constexpr (MODE == 1) {
          ((float*)Cout)[idx] = ((const float*)Extra)[idx] + acc[m][n][r];
        } else {
          float a = bf2f(((const u16*)Extra)[idx]);
          float sil = a / (1.f + exp2f(-1.4426950408889634f * a));
          ((u16*)Cout)[idx] = f2bf(sil * acc[m][n][r]);
        }
      }
    }
  }
}

// ======= GEMM 256x256xBK64, 8-phase schedule, paired-row LDS ========
// (round-5/6 structure, unchanged -- used for the FFN shapes)
template <int MODE, int BM_>
__global__ __launch_bounds__(512, 1) void gemm8p(const u16* __restrict__ A,
                                                 const u16* __restrict__ BT,
                                                 void* __restrict__ Cout,
                                                 const void* __restrict__ Extra,
                                                 int N, int K, int colMajorXcd) {
  constexpr int MM = BM_ / 64;
  constexpr int AUNIT = BM_ * 32;
  __shared__ u16 Abuf[4 * AUNIT];
  __shared__ u16 Bbuf[4 * 8192];
  const int t = threadIdx.x;
  const int w = t >> 6, l = t & 63, g = l >> 4, lq = l & 15;
  const int wm = w >> 2, wn = w & 3;

  const int gx = gridDim.x, gy = gridDim.y;
  const int nwg = gx * gy;
  int lin = colMajorXcd ? (blockIdx.x * gy + blockIdx.y)
                        : (blockIdx.y * gx + blockIdx.x);
  const int qq = nwg >> 3;
  int wg = (lin & 7) * qq + (lin >> 3);
  int bx, by;
  if (colMajorXcd) { bx = wg / gy; by = wg - bx * gy; }
  else             { by = wg / gx; bx = wg - by * gx; }
  const size_t bm = (size_t)by * BM_, bn = (size_t)bx * 256;

  const int srcrow = ((l >> 3) << 1) | (l & 1);
  const int csrc = ((((l >> 1) & 3) ^ ((l >> 3) & 3)) << 3);
  const u16* aSrc = A + (bm + w * 16 + srcrow) * (size_t)K + csrc;
  const u16* bSrc = BT + (bn + w * 16 + srcrow) * (size_t)K + csrc;
  const int rdoff = (((lq & 1) + 2 * (g ^ ((lq >> 1) & 3))) << 3);

#define STA8(DB, KS, TILE)                                                    \
  {                                                                           \
    u16* Ad = Abuf + (DB) * (2 * AUNIT) + (KS)*AUNIT + w * 512;               \
    const u16* as_ = aSrc + (size_t)(TILE)*64 + (KS)*32;                      \
    async16(Ad, as_);                                                         \
    if constexpr (BM_ == 256) async16(Ad + 4096, as_ + (size_t)128 * K);      \
  }
#define STB8(DB, KS, TILE)                                                    \
  {                                                                           \
    u16* Bd = Bbuf + (DB)*16384 + (KS)*8192 + w * 512;                        \
    const u16* bs_ = bSrc + (size_t)(TILE)*64 + (KS)*32;                      \
    async16(Bd, bs_);                                                         \
    async16(Bd + 4096, bs_ + (size_t)128 * K);                                \
  }
#define RDA8(DB, KS, MH)                                                      \
  _Pragma("unroll") for (int mm = 0; mm < MM; ++mm)                           \
      af[mm] = *(const short8*)(Abuf + (DB) * (2 * AUNIT) + (KS)*AUNIT +      \
                                (wm * (BM_ / 4) + (MH) * (BM_ / 8) + mm * 8 + \
                                 (lq >> 1)) * 64 + rdoff);
#define RDB8(DB, KS)                                                          \
  _Pragma("unroll") for (int nn = 0; nn < 4; ++nn)                            \
      bf[nn] = *(const short8*)(Bbuf + (DB)*16384 + (KS)*8192 +               \
                                (wn * 32 + nn * 8 + (lq >> 1)) * 64 + rdoff);
#define MM168(MH)                                                             \
  _Pragma("unroll") for (int mm = 0; mm < MM; ++mm)                           \
      _Pragma("unroll") for (int nn = 0; nn < 4; ++nn)                        \
          acc[(MH)*MM + mm][nn] = __builtin_amdgcn_mfma_f32_16x16x32_bf16(    \
              af[mm], bf[nn], acc[(MH)*MM + mm][nn], 0, 0, 0);
#define SYNCA                                                                 \
  asm volatile("s_barrier" ::: "memory");                                     \
  asm volatile("s_waitcnt lgkmcnt(0)" ::: "memory");                          \
  __builtin_amdgcn_sched_barrier(0);                                          \
  __builtin_amdgcn_s_setprio(1);
#define ENDP __builtin_amdgcn_s_setprio(0);
#define BAR2 asm volatile("s_barrier" ::: "memory");
#define WAITN                                                                 \
  if constexpr (BM_ == 256) asm volatile("s_waitcnt vmcnt(8)" ::: "memory");  \
  else                      asm volatile("s_waitcnt vmcnt(6)" ::: "memory");
#define WAITH                                                                 \
  if constexpr (BM_ == 256) asm volatile("s_waitcnt vmcnt(4)" ::: "memory");  \
  else                      asm volatile("s_waitcnt vmcnt(3)" ::: "memory");

  const int NT = K >> 6, NI = NT >> 1;
  f32x4 acc[2 * MM][4] = {};
  short8 af[MM > 4 ? MM : 4], bf[4];

  STA8(0, 0, 0); STB8(0, 0, 0);
  STA8(0, 1, 0); STB8(0, 1, 0);
  STA8(1, 0, 1); STB8(1, 0, 1);
  WAITN;
  BAR2;

  for (int j = 0; j < NI; ++j) {
    const int t1 = 2 * j + 1, t2 = 2 * j + 2, t3 = 2 * j + 3;
    const bool s2 = t2 < NT, s3 = t3 < NT, lastI = (j + 1 == NI);
    RDB8(0, 0); RDA8(0, 0, 0);
    STA8(1, 1, t1);
    SYNCA; MM168(0); ENDP; BAR2;
    RDA8(0, 0, 1);
    STB8(1, 1, t1);
    SYNCA; MM168(1); ENDP;
    WAITN;
    BAR2;
    RDB8(0, 1); RDA8(0, 1, 0);
    if (s2) STA8(0, 0, t2);
    SYNCA; MM168(0); ENDP; BAR2;
    RDA8(0, 1, 1);
    if (s2) STB8(0, 0, t2);
    SYNCA; MM168(1); ENDP;
    if (lastI) { WAITH; } else { WAITN; }
    BAR2;
    RDB8(1, 0); RDA8(1, 0, 0);
    if (s2) STA8(0, 1, t2);
    SYNCA; MM168(0); ENDP; BAR2;
    RDA8(1, 0, 1);
    if (s2) STB8(0, 1, t2);
    SYNCA; MM168(1); ENDP;
    if (lastI) { asm volatile("s_waitcnt vmcnt(0)" ::: "memory"); } else { WAITN; }
    BAR2;
    RDB8(1, 1); RDA8(1, 1, 0);
    if (s3) STA8(1, 0, t3);
    SYNCA; MM168(0); ENDP; BAR2;
    RDA8(1, 1, 1);
    if (s3) STB8(1, 0, t3);
    SYNCA; MM168(1); ENDP;
    if (!lastI) { WAITN; }
    BAR2;
  }
#undef STA8
#undef STB8
#undef RDA8
#undef RDB8
#undef MM168
#undef SYNCA
#undef ENDP
#undef BAR2
#undef WAITN
#undef WAITH

#pragma unroll
  for (int m = 0; m < 2 * MM; m++) {
    size_t row = bm + wm * (BM_ / 2) + m * 16 + 4 * g;
#pragma unroll
    for (int n = 0; n < 4; n++) {
      size_t col = bn + wn * 64 + n * 16 + lq;
#pragma unroll
      for (int r = 0; r < 4; r++) {
        size_t idx = (row + r) * (size_t)N + col;
        if constexpr (MODE == 0) {
          ((u16*)Cout)[idx] = f2bf(acc[m][n][r]);
        } else if constexpr (MODE == 1) {
          ((float*)Cout)[idx] = ((const float*)Extra)[idx] + acc[m][n][r];
        } else {
          float a = bf2f(((const u16*)Extra)[idx]);
          float sil = a / (1.f + exp2f(-1.4426950408889634f * a));
          ((u16*)Cout)[idx] = f2bf(sil * acc[m][n][r]);
        }
      }
    }
  }
}

// ----------------- causal flash attention (LDS-staged) --------------
__global__ __launch_bounds__(256, 3) void attn_kernel(const u16* __restrict__ QKV,
                                                      const u16* __restrict__ VT,
                                                      u16* __restrict__ CTX) {
  __shared__ u16 Ks[64 * 128];
  __shared__ u16 Vs[128 * 64];
  __shared__ u16 P_all[4][16 * 72];
  const int t = threadIdx.x;
  const int w = t >> 6, l = t & 63, g = l >> 4, lq = l & 15;
  u16* P = P_all[w];
  const int q0blk = blockIdx.x * 64;
  const int q0w = q0blk + w * 16;
  const int bh = blockIdx.y, b = bh >> 4, h = bh & 15;
  const u16* qp = QKV + (size_t)b * T_SEQ * QS + h * D_HEAD;
  const u16* kp = QKV + (size_t)b * T_SEQ * QS + E_DIM + h * D_HEAD;
  const u16* vp = VT + ((size_t)b * E_DIM + h * D_HEAD) * T_SEQ;

  short8 qf[4];
#pragma unroll
  for (int ks = 0; ks < 4; ks++)
    qf[ks] = *(const short8*)(qp + (size_t)(q0w + lq) * QS + ks * 32 + g * 8);

  f32x4 acc[8] = {};
  float m2[4], ls[4];
#pragma unroll
  for (int r = 0; r < 4; r++) { m2[r] = -1e30f; ls[r] = 0.f; }
  const float sc = 0.08838834764831845f * 1.4426950408889634f;

  const int kRow0 = 16 * w + (l >> 4);
  const int kChunk = l & 15;
  const int vRow0 = 32 * w + (l >> 3);
  const int vChunk = l & 7;

  for (int kv0 = 0; kv0 <= q0blk; kv0 += 64) {
#pragma unroll
    for (int j = 0; j < 4; j++) {
      int R = kRow0 + 4 * j;
      async16(Ks + (16 * w + 4 * j) * 128,
              kp + (size_t)(kv0 + R) * QS + ((kChunk ^ (R & 7)) << 3));
    }
#pragma unroll
    for (int j = 0; j < 4; j++) {
      int D = vRow0 + 8 * j;
      async16(Vs + (32 * w + 8 * j) * 64,
              vp + (size_t)D * T_SEQ + kv0 + ((vChunk ^ (D & 7)) << 3));
    }
    __syncthreads();

    f32x4 s[4];
#pragma unroll
    for (int ct = 0; ct < 4; ct++) {
      s[ct] = f32x4{0.f, 0.f, 0.f, 0.f};
#pragma unroll
      for (int ks = 0; ks < 4; ks++) {
        short8 kf = *(const short8*)(Ks + (ct * 16 + lq) * 128 +
                                     (((ks * 4 + g) ^ (lq & 7)) << 3));
        s[ct] = __builtin_amdgcn_mfma_f32_16x16x32_bf16(qf[ks], kf, s[ct], 0, 0, 0);
      }
    }
    float sv[4][4];
#pragma unroll
    for (int ct = 0; ct < 4; ct++)
#pragma unroll
      for (int r = 0; r < 4; r++) sv[ct][r] = s[ct][r] * sc;
    if (kv0 + 64 > q0w) {
#pragma unroll
      for (int ct = 0; ct < 4; ct++)
#pragma unroll
        for (int r = 0; r < 4; r++)
          if (kv0 + ct * 16 + lq > q0w + 4 * g + r) sv[ct][r] = -1e30f;
    }
    float mx[4];
#pragma unroll
    for (int r = 0; r < 4; r++)
      mx[r] = fmaxf(fmaxf(sv[0][r], sv[1][r]), fmaxf(sv[2][r], sv[3][r]));
#pragma unroll
    for (int off = 1; off < 16; off <<= 1)
#pragma unroll
      for (int r = 0; r < 4; r++) mx[r] = fmaxf(mx[r], __shfl_xor(mx[r], off));
#pragma unroll
    for (int r = 0; r < 4; r++) {
      float mn = fmaxf(m2[r], mx[r]);
      float sca = exp2f(m2[r] - mn);
      m2[r] = mn;
      float sum = 0.f;
#pragma unroll
      for (int ct = 0; ct < 4; ct++) {
        float pv = exp2f(sv[ct][r] - mn);
        sum += pv;
        P[(4 * g + r) * 72 + ct * 16 + lq] = f2bf(pv);
      }
      ls[r] = ls[r] * sca + sum;
#pragma unroll
      for (int n = 0; n < 8; n++) acc[n][r] *= sca;
    }
    short8 pa[2];
#pragma unroll
    for (int ks2 = 0; ks2 < 2; ks2++)
      pa[ks2] = *(const short8*)(P + lq * 72 + ks2 * 32 + g * 8);
#pragma unroll
    for (int n = 0; n < 8; n++)
#pragma unroll
      for (int ks2 = 0; ks2 < 2; ks2++) {
        short8 vf = *(const short8*)(Vs + (n * 16 + lq) * 64 +
                                     (((ks2 * 4 + g) ^ (lq & 7)) << 3));
        acc[n] = __builtin_amdgcn_mfma_f32_16x16x32_bf16(pa[ks2], vf, acc[n], 0, 0, 0);
      }
    __syncthreads();
  }

#pragma unroll
  for (int off = 1; off < 16; off <<= 1)
#pragma unroll
    for (int r = 0; r < 4; r++) ls[r] += __shfl_xor(ls[r], off);
  float inv[4];
#pragma unroll
  for (int r = 0; r < 4; r++) inv[r] = 1.f / ls[r];
  u16* cp = CTX + ((size_t)b * T_SEQ + q0w) * E_DIM + h * D_HEAD;
#pragma unroll
  for (int n = 0; n < 8; n++)
#pragma unroll
    for (int r = 0; r < 4; r++)
      cp[(size_t)(4 * g + r) * E_DIM + n * 16 + lq] = f2bf(acc[n][r] * inv[r]);
}

extern "C" void kernel_launch(void* const* d_in, const int* in_sizes, int n_in,
                              void* d_out, int out_size, void* d_ws, size_t ws_size,
                              hipStream_t stream) {
  (void)in_sizes; (void)n_in; (void)out_size; (void)ws_size;
  const float* x  = (const float*)d_in[0];
  const float* g1 = (const float*)d_in[1];
  const float* b1 = (const float*)d_in[2];
  const float* wq = (const float*)d_in[3];
  const float* wk = (const float*)d_in[4];
  const float* wv = (const float*)d_in[5];
  const float* wo = (const float*)d_in[6];
  const float* g2 = (const float*)d_in[7];
  const float* b2 = (const float*)d_in[8];
  const float* w1 = (const float*)d_in[9];
  const float* w2 = (const float*)d_in[10];
  const float* w3 = (const float*)d_in[11];
  float* out = (float*)d_out;

  const size_t EE2 = (size_t)E_DIM * E_DIM * 2;
  const size_t EF2 = (size_t)E_DIM * FFN_DIM * 2;
  const size_t ME2 = (size_t)M_ROWS * E_DIM * 2;
  char* p = (char*)d_ws;
  u16* wqkvT = (u16*)p; p += 3 * EE2;
  u16* woT = (u16*)p; p += EE2;
  u16* w1T = (u16*)p; p += EF2;
  u16* w2T = (u16*)p; p += EF2;
  u16* w3T = (u16*)p; p += EF2;
  u16* Hb  = (u16*)p; p += ME2;
  u16* QKVb = (u16*)p; p += (size_t)M_ROWS * QS * 2;
  u16* VTb = (u16*)p; p += ME2;
  u16* CTXb = (u16*)p; p += ME2;
  u16* U1b = QKVb;  // u1/gated reuses QKVb+VTb

  dim3 blk32(32, 8);
  cvt_t_kernel<<<dim3(E_DIM / 32, E_DIM / 32), blk32, 0, stream>>>(wq, wqkvT, E_DIM, E_DIM);
  cvt_t_kernel<<<dim3(E_DIM / 32, E_DIM / 32), blk32, 0, stream>>>(wk, wqkvT + E_DIM * E_DIM, E_DIM, E_DIM);
  cvt_t_kernel<<<dim3(E_DIM / 32, E_DIM / 32), blk32, 0, stream>>>(wv, wqkvT + 2 * E_DIM * E_DIM, E_DIM, E_DIM);
  cvt_t_kernel<<<dim3(E_DIM / 32, E_DIM / 32), blk32, 0, stream>>>(wo, woT, E_DIM, E_DIM);
  cvt_t_kernel<<<dim3(FFN_DIM / 32, E_DIM / 32), blk32, 0, stream>>>(w1, w1T, E_DIM, FFN_DIM);
  cvt_t_kernel<<<dim3(FFN_DIM / 32, E_DIM / 32), blk32, 0, stream>>>(w2, w2T, E_DIM, FFN_DIM);
  cvt_t_kernel<<<dim3(E_DIM / 32, FFN_DIM / 32), blk32, 0, stream>>>(w3, w3T, FFN_DIM, E_DIM);

  // attention block
  ln_kernel<<<M_ROWS, 256, 0, stream>>>(x, g1, b1, Hb);
  gemm4p<0><<<dim3(QS / 256, M_ROWS / 128), 512, 0, stream>>>(Hb, wqkvT, QKVb, nullptr, QS, E_DIM, 1);
  transpose_v_kernel<<<dim3(T_SEQ / 32, E_DIM / 32, 2), blk32, 0, stream>>>(QKVb, VTb);
  attn_kernel<<<dim3(T_SEQ / 64, 2 * N_HEAD), 256, 0, stream>>>(QKVb, VTb, CTXb);
  gemm4p<1><<<dim3(E_DIM / 256, M_ROWS / 128), 512, 0, stream>>>(CTXb, woT, out, x, E_DIM, E_DIM, 1);

  // SwiGLU MLP block
  ln_kernel<<<M_ROWS, 256, 0, stream>>>(out, g2, b2, Hb);
  gemm8p<0, 256><<<dim3(FFN_DIM / 256, M_ROWS / 256), 512, 0, stream>>>(Hb, w1T, U1b, nullptr, FFN_DIM, E_DIM, 1);
  gemm8p<2, 256><<<dim3(FFN_DIM / 256, M_ROWS / 256), 512, 0, stream>>>(Hb, w2T, U1b, U1b, FFN_DIM, E_DIM, 1);
  gemm4p<1><<<dim3(E_DIM / 256, M_ROWS / 128), 512, 0, stream>>>(U1b, w3T, out, out, E_DIM, FFN_DIM, 1);
}

// Round 9
// 971.495 us; speedup vs baseline: 1.0023x; 1.0023x over previous
//
#include <hip/hip_runtime.h>

// Transformer layer, bf16 MFMA compute, fp32 I/O.
// B=2 T=2048 E=2048 H=16 DH=128 FFN=8192. Needs ~235MB workspace.

#define T_SEQ 2048
#define E_DIM 2048
#define N_HEAD 16
#define D_HEAD 128
#define FFN_DIM 8192
#define M_ROWS 4096  // B*T
#define QS (3 * E_DIM)  // fused QKV row stride

typedef unsigned short u16;
typedef short short8 __attribute__((ext_vector_type(8)));
typedef float f32x4 __attribute__((ext_vector_type(4)));

#define DEV __device__ __forceinline__

DEV u16 f2bf(float f) {
  unsigned u = __float_as_uint(f);
  u += 0x7fffu + ((u >> 16) & 1u);
  return (u16)(u >> 16);
}
DEV float bf2f(u16 h) { return __uint_as_float(((unsigned)h) << 16); }

DEV void async16(void* lds, const void* g) {
  __builtin_amdgcn_global_load_lds((const __attribute__((address_space(1))) void*)g,
                                   (__attribute__((address_space(3))) void*)lds, 16, 0, 0);
}

// ---------------- LayerNorm: fp32 [rows][E] -> bf16 -----------------
__global__ __launch_bounds__(256) void ln_kernel(const float* __restrict__ x,
                                                 const float* __restrict__ gw,
                                                 const float* __restrict__ bw,
                                                 u16* __restrict__ out) {
  int row = blockIdx.x;
  int t = threadIdx.x;
  const float4* xr = (const float4*)(x + (size_t)row * E_DIM);
  float4 a = xr[t], c = xr[t + 256];
  float s = a.x + a.y + a.z + a.w + c.x + c.y + c.z + c.w;
  float q = a.x * a.x + a.y * a.y + a.z * a.z + a.w * a.w +
            c.x * c.x + c.y * c.y + c.z * c.z + c.w * c.w;
  for (int off = 32; off > 0; off >>= 1) {
    s += __shfl_down(s, off);
    q += __shfl_down(q, off);
  }
  __shared__ float red[8];
  if ((t & 63) == 0) { red[(t >> 6) * 2] = s; red[(t >> 6) * 2 + 1] = q; }
  __syncthreads();
  s = red[0] + red[2] + red[4] + red[6];
  q = red[1] + red[3] + red[5] + red[7];
  float mu = s * (1.f / E_DIM);
  float rs = rsqrtf(q * (1.f / E_DIM) - mu * mu + 1e-5f);
  const float4* g4 = (const float4*)gw;
  const float4* b4 = (const float4*)bw;
  float4 g0 = g4[t], g1v = g4[t + 256], e0 = b4[t], e1 = b4[t + 256];
  ushort4 o0, o1;
  o0.x = f2bf((a.x - mu) * rs * g0.x + e0.x);
  o0.y = f2bf((a.y - mu) * rs * g0.y + e0.y);
  o0.z = f2bf((a.z - mu) * rs * g0.z + e0.z);
  o0.w = f2bf((a.w - mu) * rs * g0.w + e0.w);
  o1.x = f2bf((c.x - mu) * rs * g1v.x + e1.x);
  o1.y = f2bf((c.y - mu) * rs * g1v.y + e1.y);
  o1.z = f2bf((c.z - mu) * rs * g1v.z + e1.z);
  o1.w = f2bf((c.w - mu) * rs * g1v.w + e1.w);
  ((ushort4*)(out + (size_t)row * E_DIM))[t] = o0;
  ((ushort4*)(out + (size_t)row * E_DIM))[t + 256] = o1;
}

// ------- convert+transpose: fp32 W[K][N] -> bf16 WT[N][K] -----------
__global__ __launch_bounds__(256) void cvt_t_kernel(const float* __restrict__ W,
                                                    u16* __restrict__ WT,
                                                    int Kd, int Nd) {
  __shared__ float tile[32][33];
  int tx = threadIdx.x, ty = threadIdx.y;
  int n0 = blockIdx.x * 32, k0 = blockIdx.y * 32;
#pragma unroll
  for (int i = 0; i < 4; i++)
    tile[ty + i * 8][tx] = W[(size_t)(k0 + ty + i * 8) * Nd + n0 + tx];
  __syncthreads();
#pragma unroll
  for (int i = 0; i < 4; i++)
    WT[(size_t)(n0 + ty + i * 8) * Kd + k0 + tx] = f2bf(tile[tx][ty + i * 8]);
}

// -- transpose V from fused QKV: bf16 [B*T][QS] col 4096+ -> [B][E][T]
__global__ __launch_bounds__(256) void transpose_v_kernel(const u16* __restrict__ qkv,
                                                          u16* __restrict__ vt) {
  __shared__ u16 tile[32][33];
  int tx = threadIdx.x, ty = threadIdx.y;
  int b = blockIdx.z;
  int t0 = blockIdx.x * 32, e0 = blockIdx.y * 32;
#pragma unroll
  for (int i = 0; i < 4; i++)
    tile[ty + i * 8][tx] =
        qkv[(size_t)(b * T_SEQ + t0 + ty + i * 8) * QS + 2 * E_DIM + e0 + tx];
  __syncthreads();
#pragma unroll
  for (int i = 0; i < 4; i++)
    vt[((size_t)b * E_DIM + e0 + ty + i * 8) * T_SEQ + t0 + tx] = tile[tx][ty + i * 8];
}

// ==== GEMM 128x256xBK64, 4-phase pipeline, PINNED read-ahead ========
// C[M][N] = A[M][K] * BT[N][K]^T.  512 thr = 8 waves (2Mx4N), wave
// tile 64x64, paired-row LDS (0-conflict).  Per phase:
//   {ds_read NEXT frags (alt reg set); stage 1 A-unit + 1 B-unit;
//    sched_barrier(0)   <- pins reads/stages BEFORE the MFMA cluster
//    setprio(1); 16 MFMA on CURRENT set; setprio(0);
//    sched_barrier(0); vmcnt(3); s_barrier}
// The only lgkm waits are compiler-counted before the NEXT phase's
// MFMA, so LDS service + stage tail overlap this phase's MFMA.
// Stagger: P0 stages db1ks1(tb) P1 db0ks0(t2) P2 db0ks1(t2)
// P3 db1ks0(t3);  reads: P0->db0ks1 P1->db1ks0 P2->db1ks1 P3->db0ks0.
// vmcnt(3) at each phase end forces the 1-phase-ago stages complete
// (2-phase stagger depth requires it).  Last iter drains.
// MODE 0: bf16 C.  MODE 1: Cout(f32)=Extra(f32)+acc.
// MODE 2: Cout(bf16)=silu(Extra bf16)*acc.
template <int MODE>
__global__ __launch_bounds__(512, 1) void gemm4p(const u16* __restrict__ A,
                                                 const u16* __restrict__ BT,
                                                 void* __restrict__ Cout,
                                                 const void* __restrict__ Extra,
                                                 int N, int K, int colMajorXcd) {
  __shared__ u16 Abuf[4 * 4096];   // 32 KB
  __shared__ u16 Bbuf[4 * 8192];   // 64 KB
  const int t = threadIdx.x;
  const int w = t >> 6, l = t & 63, g = l >> 4, lq = l & 15;
  const int wm = w >> 2, wn = w & 3;

  // T1: bijective XCD swizzle (all grids have nwg % 8 == 0)
  const int gx = gridDim.x, gy = gridDim.y;
  const int nwg = gx * gy;
  int lin = colMajorXcd ? (blockIdx.x * gy + blockIdx.y)
                        : (blockIdx.y * gx + blockIdx.x);
  const int qq = nwg >> 3;
  int wg = (lin & 7) * qq + (lin >> 3);
  int bx, by;
  if (colMajorXcd) { bx = wg / gy; by = wg - bx * gy; }
  else             { by = wg / gx; bx = wg - by * gx; }
  const size_t bm = (size_t)by * 128, bn = (size_t)bx * 256;

  // staging lane constants (paired-row)
  const int srcrow = ((l >> 3) << 1) | (l & 1);
  const int csrc = ((((l >> 1) & 3) ^ ((l >> 3) & 3)) << 3);
  const u16* aSrc = A + (bm + w * 16 + srcrow) * (size_t)K + csrc;
  const u16* bSrc = BT + (bn + w * 16 + srcrow) * (size_t)K + csrc;
  const int rdoff = (((lq & 1) + 2 * (g ^ ((lq >> 1) & 3))) << 3);

#define STA(DB, KS, TILE)                                                     \
  async16(Abuf + (DB)*8192 + (KS)*4096 + w * 512,                             \
          aSrc + (size_t)(TILE)*64 + (KS)*32);
#define STB(DB, KS, TILE)                                                     \
  {                                                                           \
    u16* Bd = Bbuf + (DB)*16384 + (KS)*8192 + w * 512;                        \
    const u16* bs_ = bSrc + (size_t)(TILE)*64 + (KS)*32;                      \
    async16(Bd, bs_);                                                         \
    async16(Bd + 4096, bs_ + (size_t)128 * K);                                \
  }
#define RD_A(DST, DB, KS)                                                     \
  _Pragma("unroll") for (int m2 = 0; m2 < 4; ++m2)                            \
      DST[m2] = *(const short8*)(Abuf + (DB)*8192 + (KS)*4096 +               \
                                 (wm * 32 + m2 * 8 + (lq >> 1)) * 64 + rdoff);
#define RD_B(DST, DB, KS)                                                     \
  _Pragma("unroll") for (int nn = 0; nn < 4; ++nn)                            \
      DST[nn] = *(const short8*)(Bbuf + (DB)*16384 + (KS)*8192 +              \
                                 (wn * 32 + nn * 8 + (lq >> 1)) * 64 + rdoff);
#define MMA(AF, BF)                                                           \
  _Pragma("unroll") for (int m2 = 0; m2 < 4; ++m2)                            \
      _Pragma("unroll") for (int nn = 0; nn < 4; ++nn)                        \
          acc[m2][nn] = __builtin_amdgcn_mfma_f32_16x16x32_bf16(              \
              AF[m2], BF[nn], acc[m2][nn], 0, 0, 0);
#define PIN __builtin_amdgcn_sched_barrier(0);
#define ENDPH(VN_STR)                                                         \
  __builtin_amdgcn_s_setprio(0);                                              \
  __builtin_amdgcn_sched_barrier(0);                                          \
  asm volatile("s_waitcnt vmcnt(" VN_STR ")" ::: "memory");                   \
  __builtin_amdgcn_s_barrier();

  const int NT = K >> 6, NI = NT >> 1;
  f32x4 acc[4][4] = {};
  short8 af0[4], bf0[4], af1[4], bf1[4];

  // prologue: stage t0 both halves + t1-ks0 (9 loads/thread)
  STA(0, 0, 0); STB(0, 0, 0);
  STA(0, 1, 0); STB(0, 1, 0);
  STA(1, 0, 1); STB(1, 0, 1);
  asm volatile("s_waitcnt vmcnt(3)" ::: "memory");  // t0 fully resident
  __builtin_amdgcn_s_barrier();
  RD_A(af0, 0, 0); RD_B(bf0, 0, 0);

  for (int j = 0; j < NI; ++j) {
    const int tb = 2 * j + 1, t2 = 2 * j + 2, t3 = 2 * j + 3;
    const bool li = (j + 1 == NI);
    // P0: read set1 <- db0ks1; stage db1ks1 <- tb; mfma set0 (db0ks0)
    RD_A(af1, 0, 1); RD_B(bf1, 0, 1);
    STA(1, 1, tb); STB(1, 1, tb);
    PIN
    __builtin_amdgcn_s_setprio(1);
    MMA(af0, bf0);
    ENDPH("3")
    // P1: read set0 <- db1ks0; stage db0ks0 <- t2; mfma set1 (db0ks1)
    RD_A(af0, 1, 0); RD_B(bf0, 1, 0);
    if (!li) { STA(0, 0, t2); STB(0, 0, t2); }
    PIN
    __builtin_amdgcn_s_setprio(1);
    MMA(af1, bf1);
    if (!li) { ENDPH("3") } else { ENDPH("0") }
    // P2: read set1 <- db1ks1; stage db0ks1 <- t2; mfma set0 (db1ks0)
    RD_A(af1, 1, 1); RD_B(bf1, 1, 1);
    if (!li) { STA(0, 1, t2); STB(0, 1, t2); }
    PIN
    __builtin_amdgcn_s_setprio(1);
    MMA(af0, bf0);
    if (!li) { ENDPH("3") } else { ENDPH("0") }
    // P3: read set0 <- db0ks0(t2); stage db1ks0 <- t3; mfma set1 (db1ks1)
    if (!li) {
      RD_A(af0, 0, 0); RD_B(bf0, 0, 0);
      STA(1, 0, t3); STB(1, 0, t3);
    }
    PIN
    __builtin_amdgcn_s_setprio(1);
    MMA(af1, bf1);
    if (!li) { ENDPH("3") } else { __builtin_amdgcn_s_setprio(0); }
  }
#undef STA
#undef STB
#undef RD_A
#undef RD_B
#undef MMA
#undef PIN
#undef ENDPH

#pragma unroll
  for (int m = 0; m < 4; m++) {
    size_t row = bm + wm * 64 + m * 16 + 4 * g;
#pragma unroll
    for (int n = 0; n < 4; n++) {
      size_t col = bn + wn * 64 + n * 16 + lq;
#pragma unroll
      for (int r = 0; r < 4; r++) {
        size_t idx = (row + r) * (size_t)N + col;
        if constexpr (MODE == 0) {
          ((u16*)Cout)[idx] = f2bf(acc[m][n][r]);
        } else if constexpr (MODE == 1) {
          ((float*)Cout)[idx] = ((const float*)Extra)[idx] + acc[m][n][r];
        } else {
          float a = bf2f(((const u16*)Extra)[idx]);
          float sil = a / (1.f + exp2f(-1.4426950408889634f * a));
          ((u16*)Cout)[idx] = f2bf(sil * acc[m][n][r]);
        }
      }
    }
  }
}

// ======= GEMM 256x256xBK64, 8-phase schedule, paired-row LDS ========
// (round-6 structure; barriers switched to builtin -- used for FFN)
template <int MODE, int BM_>
__global__ __launch_bounds__(512, 1) void gemm8p(const u16* __restrict__ A,
                                                 const u16* __restrict__ BT,
                                                 void* __restrict__ Cout,
                                                 const void* __restrict__ Extra,
                                                 int N, int K, int colMajorXcd) {
  constexpr int MM = BM_ / 64;
  constexpr int AUNIT = BM_ * 32;
  __shared__ u16 Abuf[4 * AUNIT];
  __shared__ u16 Bbuf[4 * 8192];
  const int t = threadIdx.x;
  const int w = t >> 6, l = t & 63, g = l >> 4, lq = l & 15;
  const int wm = w >> 2, wn = w & 3;

  const int gx = gridDim.x, gy = gridDim.y;
  const int nwg = gx * gy;
  int lin = colMajorXcd ? (blockIdx.x * gy + blockIdx.y)
                        : (blockIdx.y * gx + blockIdx.x);
  const int qq = nwg >> 3;
  int wg = (lin & 7) * qq + (lin >> 3);
  int bx, by;
  if (colMajorXcd) { bx = wg / gy; by = wg - bx * gy; }
  else             { by = wg / gx; bx = wg - by * gx; }
  const size_t bm = (size_t)by * BM_, bn = (size_t)bx * 256;

  const int srcrow = ((l >> 3) << 1) | (l & 1);
  const int csrc = ((((l >> 1) & 3) ^ ((l >> 3) & 3)) << 3);
  const u16* aSrc = A + (bm + w * 16 + srcrow) * (size_t)K + csrc;
  const u16* bSrc = BT + (bn + w * 16 + srcrow) * (size_t)K + csrc;
  const int rdoff = (((lq & 1) + 2 * (g ^ ((lq >> 1) & 3))) << 3);

#define STA8(DB, KS, TILE)                                                    \
  {                                                                           \
    u16* Ad = Abuf + (DB) * (2 * AUNIT) + (KS)*AUNIT + w * 512;               \
    const u16* as_ = aSrc + (size_t)(TILE)*64 + (KS)*32;                      \
    async16(Ad, as_);                                                         \
    if constexpr (BM_ == 256) async16(Ad + 4096, as_ + (size_t)128 * K);      \
  }
#define STB8(DB, KS, TILE)                                                    \
  {                                                                           \
    u16* Bd = Bbuf + (DB)*16384 + (KS)*8192 + w * 512;                        \
    const u16* bs_ = bSrc + (size_t)(TILE)*64 + (KS)*32;                      \
    async16(Bd, bs_);                                                         \
    async16(Bd + 4096, bs_ + (size_t)128 * K);                                \
  }
#define RDA8(DB, KS, MH)                                                      \
  _Pragma("unroll") for (int mm = 0; mm < MM; ++mm)                           \
      af[mm] = *(const short8*)(Abuf + (DB) * (2 * AUNIT) + (KS)*AUNIT +      \
                                (wm * (BM_ / 4) + (MH) * (BM_ / 8) + mm * 8 + \
                                 (lq >> 1)) * 64 + rdoff);
#define RDB8(DB, KS)                                                          \
  _Pragma("unroll") for (int nn = 0; nn < 4; ++nn)                            \
      bf[nn] = *(const short8*)(Bbuf + (DB)*16384 + (KS)*8192 +               \
                                (wn * 32 + nn * 8 + (lq >> 1)) * 64 + rdoff);
#define MM168(MH)                                                             \
  _Pragma("unroll") for (int mm = 0; mm < MM; ++mm)                           \
      _Pragma("unroll") for (int nn = 0; nn < 4; ++nn)                        \
          acc[(MH)*MM + mm][nn] = __builtin_amdgcn_mfma_f32_16x16x32_bf16(    \
              af[mm], bf[nn], acc[(MH)*MM + mm][nn], 0, 0, 0);
#define SYNCA                                                                 \
  __builtin_amdgcn_s_barrier();                                               \
  asm volatile("s_waitcnt lgkmcnt(0)" ::: "memory");                          \
  __builtin_amdgcn_sched_barrier(0);                                          \
  __builtin_amdgcn_s_setprio(1);
#define ENDP __builtin_amdgcn_s_setprio(0);
#define BAR2 __builtin_amdgcn_s_barrier();
#define WAITN                                                                 \
  if constexpr (BM_ == 256) asm volatile("s_waitcnt vmcnt(8)" ::: "memory");  \
  else                      asm volatile("s_waitcnt vmcnt(6)" ::: "memory");
#define WAITH                                                                 \
  if constexpr (BM_ == 256) asm volatile("s_waitcnt vmcnt(4)" ::: "memory");  \
  else                      asm volatile("s_waitcnt vmcnt(3)" ::: "memory");

  const int NT = K >> 6, NI = NT >> 1;
  f32x4 acc[2 * MM][4] = {};
  short8 af[MM > 4 ? MM : 4], bf[4];

  STA8(0, 0, 0); STB8(0, 0, 0);
  STA8(0, 1, 0); STB8(0, 1, 0);
  STA8(1, 0, 1); STB8(1, 0, 1);
  WAITN;
  BAR2;

  for (int j = 0; j < NI; ++j) {
    const int t1 = 2 * j + 1, t2 = 2 * j + 2, t3 = 2 * j + 3;
    const bool s2 = t2 < NT, s3 = t3 < NT, lastI = (j + 1 == NI);
    RDB8(0, 0); RDA8(0, 0, 0);
    STA8(1, 1, t1);
    SYNCA; MM168(0); ENDP; BAR2;
    RDA8(0, 0, 1);
    STB8(1, 1, t1);
    SYNCA; MM168(1); ENDP;
    WAITN;
    BAR2;
    RDB8(0, 1); RDA8(0, 1, 0);
    if (s2) STA8(0, 0, t2);
    SYNCA; MM168(0); ENDP; BAR2;
    RDA8(0, 1, 1);
    if (s2) STB8(0, 0, t2);
    SYNCA; MM168(1); ENDP;
    if (lastI) { WAITH; } else { WAITN; }
    BAR2;
    RDB8(1, 0); RDA8(1, 0, 0);
    if (s2) STA8(0, 1, t2);
    SYNCA; MM168(0); ENDP; BAR2;
    RDA8(1, 0, 1);
    if (s2) STB8(0, 1, t2);
    SYNCA; MM168(1); ENDP;
    if (lastI) { asm volatile("s_waitcnt vmcnt(0)" ::: "memory"); } else { WAITN; }
    BAR2;
    RDB8(1, 1); RDA8(1, 1, 0);
    if (s3) STA8(1, 0, t3);
    SYNCA; MM168(0); ENDP; BAR2;
    RDA8(1, 1, 1);
    if (s3) STB8(1, 0, t3);
    SYNCA; MM168(1); ENDP;
    if (!lastI) { WAITN; }
    BAR2;
  }
#undef STA8
#undef STB8
#undef RDA8
#undef RDB8
#undef MM168
#undef SYNCA
#undef ENDP
#undef BAR2
#undef WAITN
#undef WAITH

#pragma unroll
  for (int m = 0; m < 2 * MM; m++) {
    size_t row = bm + wm * (BM_ / 2) + m * 16 + 4 * g;
#pragma unroll
    for (int n = 0; n < 4; n++) {
      size_t col = bn + wn * 64 + n * 16 + lq;
#pragma unroll
      for (int r = 0; r < 4; r++) {
        size_t idx = (row + r) * (size_t)N + col;
        if constexpr (MODE == 0) {
          ((u16*)Cout)[idx] = f2bf(acc[m][n][r]);
        } else if constexpr (MODE == 1) {
          ((float*)Cout)[idx] = ((const float*)Extra)[idx] + acc[m][n][r];
        } else {
          float a = bf2f(((const u16*)Extra)[idx]);
          float sil = a / (1.f + exp2f(-1.4426950408889634f * a));
          ((u16*)Cout)[idx] = f2bf(sil * acc[m][n][r]);
        }
      }
    }
  }
}

// ----------------- causal flash attention (LDS-staged) --------------
__global__ __launch_bounds__(256, 3) void attn_kernel(const u16* __restrict__ QKV,
                                                      const u16* __restrict__ VT,
                                                      u16* __restrict__ CTX) {
  __shared__ u16 Ks[64 * 128];
  __shared__ u16 Vs[128 * 64];
  __shared__ u16 P_all[4][16 * 72];
  const int t = threadIdx.x;
  const int w = t >> 6, l = t & 63, g = l >> 4, lq = l & 15;
  u16* P = P_all[w];
  const int q0blk = blockIdx.x * 64;
  const int q0w = q0blk + w * 16;
  const int bh = blockIdx.y, b = bh >> 4, h = bh & 15;
  const u16* qp = QKV + (size_t)b * T_SEQ * QS + h * D_HEAD;
  const u16* kp = QKV + (size_t)b * T_SEQ * QS + E_DIM + h * D_HEAD;
  const u16* vp = VT + ((size_t)b * E_DIM + h * D_HEAD) * T_SEQ;

  short8 qf[4];
#pragma unroll
  for (int ks = 0; ks < 4; ks++)
    qf[ks] = *(const short8*)(qp + (size_t)(q0w + lq) * QS + ks * 32 + g * 8);

  f32x4 acc[8] = {};
  float m2[4], ls[4];
#pragma unroll
  for (int r = 0; r < 4; r++) { m2[r] = -1e30f; ls[r] = 0.f; }
  const float sc = 0.08838834764831845f * 1.4426950408889634f;

  const int kRow0 = 16 * w + (l >> 4);
  const int kChunk = l & 15;
  const int vRow0 = 32 * w + (l >> 3);
  const int vChunk = l & 7;

  for (int kv0 = 0; kv0 <= q0blk; kv0 += 64) {
#pragma unroll
    for (int j = 0; j < 4; j++) {
      int R = kRow0 + 4 * j;
      async16(Ks + (16 * w + 4 * j) * 128,
              kp + (size_t)(kv0 + R) * QS + ((kChunk ^ (R & 7)) << 3));
    }
#pragma unroll
    for (int j = 0; j < 4; j++) {
      int D = vRow0 + 8 * j;
      async16(Vs + (32 * w + 8 * j) * 64,
              vp + (size_t)D * T_SEQ + kv0 + ((vChunk ^ (D & 7)) << 3));
    }
    __syncthreads();

    f32x4 s[4];
#pragma unroll
    for (int ct = 0; ct < 4; ct++) {
      s[ct] = f32x4{0.f, 0.f, 0.f, 0.f};
#pragma unroll
      for (int ks = 0; ks < 4; ks++) {
        short8 kf = *(const short8*)(Ks + (ct * 16 + lq) * 128 +
                                     (((ks * 4 + g) ^ (lq & 7)) << 3));
        s[ct] = __builtin_amdgcn_mfma_f32_16x16x32_bf16(qf[ks], kf, s[ct], 0, 0, 0);
      }
    }
    float sv[4][4];
#pragma unroll
    for (int ct = 0; ct < 4; ct++)
#pragma unroll
      for (int r = 0; r < 4; r++) sv[ct][r] = s[ct][r] * sc;
    if (kv0 + 64 > q0w) {
#pragma unroll
      for (int ct = 0; ct < 4; ct++)
#pragma unroll
        for (int r = 0; r < 4; r++)
          if (kv0 + ct * 16 + lq > q0w + 4 * g + r) sv[ct][r] = -1e30f;
    }
    float mx[4];
#pragma unroll
    for (int r = 0; r < 4; r++)
      mx[r] = fmaxf(fmaxf(sv[0][r], sv[1][r]), fmaxf(sv[2][r], sv[3][r]));
#pragma unroll
    for (int off = 1; off < 16; off <<= 1)
#pragma unroll
      for (int r = 0; r < 4; r++) mx[r] = fmaxf(mx[r], __shfl_xor(mx[r], off));
#pragma unroll
    for (int r = 0; r < 4; r++) {
      float mn = fmaxf(m2[r], mx[r]);
      float sca = exp2f(m2[r] - mn);
      m2[r] = mn;
      float sum = 0.f;
#pragma unroll
      for (int ct = 0; ct < 4; ct++) {
        float pv = exp2f(sv[ct][r] - mn);
        sum += pv;
        P[(4 * g + r) * 72 + ct * 16 + lq] = f2bf(pv);
      }
      ls[r] = ls[r] * sca + sum;
#pragma unroll
      for (int n = 0; n < 8; n++) acc[n][r] *= sca;
    }
    short8 pa[2];
#pragma unroll
    for (int ks2 = 0; ks2 < 2; ks2++)
      pa[ks2] = *(const short8*)(P + lq * 72 + ks2 * 32 + g * 8);
#pragma unroll
    for (int n = 0; n < 8; n++)
#pragma unroll
      for (int ks2 = 0; ks2 < 2; ks2++) {
        short8 vf = *(const short8*)(Vs + (n * 16 + lq) * 64 +
                                     (((ks2 * 4 + g) ^ (lq & 7)) << 3));
        acc[n] = __builtin_amdgcn_mfma_f32_16x16x32_bf16(pa[ks2], vf, acc[n], 0, 0, 0);
      }
    __syncthreads();
  }

#pragma unroll
  for (int off = 1; off < 16; off <<= 1)
#pragma unroll
    for (int r = 0; r < 4; r++) ls[r] += __shfl_xor(ls[r], off);
  float inv[4];
#pragma unroll
  for (int r = 0; r < 4; r++) inv[r] = 1.f / ls[r];
  u16* cp = CTX + ((size_t)b * T_SEQ + q0w) * E_DIM + h * D_HEAD;
#pragma unroll
  for (int n = 0; n < 8; n++)
#pragma unroll
    for (int r = 0; r < 4; r++)
      cp[(size_t)(4 * g + r) * E_DIM + n * 16 + lq] = f2bf(acc[n][r] * inv[r]);
}

extern "C" void kernel_launch(void* const* d_in, const int* in_sizes, int n_in,
                              void* d_out, int out_size, void* d_ws, size_t ws_size,
                              hipStream_t stream) {
  (void)in_sizes; (void)n_in; (void)out_size; (void)ws_size;
  const float* x  = (const float*)d_in[0];
  const float* g1 = (const float*)d_in[1];
  const float* b1 = (const float*)d_in[2];
  const float* wq = (const float*)d_in[3];
  const float* wk = (const float*)d_in[4];
  const float* wv = (const float*)d_in[5];
  const float* wo = (const float*)d_in[6];
  const float* g2 = (const float*)d_in[7];
  const float* b2 = (const float*)d_in[8];
  const float* w1 = (const float*)d_in[9];
  const float* w2 = (const float*)d_in[10];
  const float* w3 = (const float*)d_in[11];
  float* out = (float*)d_out;

  const size_t EE2 = (size_t)E_DIM * E_DIM * 2;
  const size_t EF2 = (size_t)E_DIM * FFN_DIM * 2;
  const size_t ME2 = (size_t)M_ROWS * E_DIM * 2;
  char* p = (char*)d_ws;
  u16* wqkvT = (u16*)p; p += 3 * EE2;
  u16* woT = (u16*)p; p += EE2;
  u16* w1T = (u16*)p; p += EF2;
  u16* w2T = (u16*)p; p += EF2;
  u16* w3T = (u16*)p; p += EF2;
  u16* Hb  = (u16*)p; p += ME2;
  u16* QKVb = (u16*)p; p += (size_t)M_ROWS * QS * 2;
  u16* VTb = (u16*)p; p += ME2;
  u16* CTXb = (u16*)p; p += ME2;
  u16* U1b = QKVb;  // u1/gated reuses QKVb+VTb

  dim3 blk32(32, 8);
  cvt_t_kernel<<<dim3(E_DIM / 32, E_DIM / 32), blk32, 0, stream>>>(wq, wqkvT, E_DIM, E_DIM);
  cvt_t_kernel<<<dim3(E_DIM / 32, E_DIM / 32), blk32, 0, stream>>>(wk, wqkvT + E_DIM * E_DIM, E_DIM, E_DIM);
  cvt_t_kernel<<<dim3(E_DIM / 32, E_DIM / 32), blk32, 0, stream>>>(wv, wqkvT + 2 * E_DIM * E_DIM, E_DIM, E_DIM);
  cvt_t_kernel<<<dim3(E_DIM / 32, E_DIM / 32), blk32, 0, stream>>>(wo, woT, E_DIM, E_DIM);
  cvt_t_kernel<<<dim3(FFN_DIM / 32, E_DIM / 32), blk32, 0, stream>>>(w1, w1T, E_DIM, FFN_DIM);
  cvt_t_kernel<<<dim3(FFN_DIM / 32, E_DIM / 32), blk32, 0, stream>>>(w2, w2T, E_DIM, FFN_DIM);
  cvt_t_kernel<<<dim3(E_DIM / 32, FFN_DIM / 32), blk32, 0, stream>>>(w3, w3T, FFN_DIM, E_DIM);

  // attention block
  ln_kernel<<<M_ROWS, 256, 0, stream>>>(x, g1, b1, Hb);
  gemm4p<0><<<dim3(QS / 256, M_ROWS / 128), 512, 0, stream>>>(Hb, wqkvT, QKVb, nullptr, QS, E_DIM, 1);
  transpose_v_kernel<<<dim3(T_SEQ / 32, E_DIM / 32, 2), blk32, 0, stream>>>(QKVb, VTb);
  attn_kernel<<<dim3(T_SEQ / 64, 2 * N_HEAD), 256, 0, stream>>>(QKVb, VTb, CTXb);
  gemm4p<1><<<dim3(E_DIM / 256, M_ROWS / 128), 512, 0, stream>>>(CTXb, woT, out, x, E_DIM, E_DIM, 1);

  // SwiGLU MLP block
  ln_kernel<<<M_ROWS, 256, 0, stream>>>(out, g2, b2, Hb);
  gemm8p<0, 256><<<dim3(FFN_DIM / 256, M_ROWS / 256), 512, 0, stream>>>(Hb, w1T, U1b, nullptr, FFN_DIM, E_DIM, 1);
  gemm8p<2, 256><<<dim3(FFN_DIM / 256, M_ROWS / 256), 512, 0, stream>>>(Hb, w2T, U1b, U1b, FFN_DIM, E_DIM, 1);
  gemm4p<1><<<dim3(E_DIM / 256, M_ROWS / 128), 512, 0, stream>>>(U1b, w3T, out, out, E_DIM, FFN_DIM, 1);
}

// Round 10
// 942.318 us; speedup vs baseline: 1.0333x; 1.0310x over previous
//
#include <hip/hip_runtime.h>

// Transformer layer, bf16 MFMA compute, fp32 I/O.
// B=2 T=2048 E=2048 H=16 DH=128 FFN=8192. Needs ~235MB workspace.

#define T_SEQ 2048
#define E_DIM 2048
#define N_HEAD 16
#define D_HEAD 128
#define FFN_DIM 8192
#define M_ROWS 4096  // B*T
#define QS (3 * E_DIM)  // fused QKV row stride

typedef unsigned short u16;
typedef short short8 __attribute__((ext_vector_type(8)));
typedef float f32x4 __attribute__((ext_vector_type(4)));

#define DEV __device__ __forceinline__

DEV u16 f2bf(float f) {
  unsigned u = __float_as_uint(f);
  u += 0x7fffu + ((u >> 16) & 1u);
  return (u16)(u >> 16);
}
DEV float bf2f(u16 h) { return __uint_as_float(((unsigned)h) << 16); }

DEV void async16(void* lds, const void* g) {
  __builtin_amdgcn_global_load_lds((const __attribute__((address_space(1))) void*)g,
                                   (__attribute__((address_space(3))) void*)lds, 16, 0, 0);
}

// ---------------- LayerNorm: fp32 [rows][E] -> bf16 -----------------
__global__ __launch_bounds__(256) void ln_kernel(const float* __restrict__ x,
                                                 const float* __restrict__ gw,
                                                 const float* __restrict__ bw,
                                                 u16* __restrict__ out) {
  int row = blockIdx.x;
  int t = threadIdx.x;
  const float4* xr = (const float4*)(x + (size_t)row * E_DIM);
  float4 a = xr[t], c = xr[t + 256];
  float s = a.x + a.y + a.z + a.w + c.x + c.y + c.z + c.w;
  float q = a.x * a.x + a.y * a.y + a.z * a.z + a.w * a.w +
            c.x * c.x + c.y * c.y + c.z * c.z + c.w * c.w;
  for (int off = 32; off > 0; off >>= 1) {
    s += __shfl_down(s, off);
    q += __shfl_down(q, off);
  }
  __shared__ float red[8];
  if ((t & 63) == 0) { red[(t >> 6) * 2] = s; red[(t >> 6) * 2 + 1] = q; }
  __syncthreads();
  s = red[0] + red[2] + red[4] + red[6];
  q = red[1] + red[3] + red[5] + red[7];
  float mu = s * (1.f / E_DIM);
  float rs = rsqrtf(q * (1.f / E_DIM) - mu * mu + 1e-5f);
  const float4* g4 = (const float4*)gw;
  const float4* b4 = (const float4*)bw;
  float4 g0 = g4[t], g1v = g4[t + 256], e0 = b4[t], e1 = b4[t + 256];
  ushort4 o0, o1;
  o0.x = f2bf((a.x - mu) * rs * g0.x + e0.x);
  o0.y = f2bf((a.y - mu) * rs * g0.y + e0.y);
  o0.z = f2bf((a.z - mu) * rs * g0.z + e0.z);
  o0.w = f2bf((a.w - mu) * rs * g0.w + e0.w);
  o1.x = f2bf((c.x - mu) * rs * g1v.x + e1.x);
  o1.y = f2bf((c.y - mu) * rs * g1v.y + e1.y);
  o1.z = f2bf((c.z - mu) * rs * g1v.z + e1.z);
  o1.w = f2bf((c.w - mu) * rs * g1v.w + e1.w);
  ((ushort4*)(out + (size_t)row * E_DIM))[t] = o0;
  ((ushort4*)(out + (size_t)row * E_DIM))[t + 256] = o1;
}

// ------- convert+transpose: fp32 W[K][N] -> bf16 WT[N][K] -----------
__global__ __launch_bounds__(256) void cvt_t_kernel(const float* __restrict__ W,
                                                    u16* __restrict__ WT,
                                                    int Kd, int Nd) {
  __shared__ float tile[32][33];
  int tx = threadIdx.x, ty = threadIdx.y;
  int n0 = blockIdx.x * 32, k0 = blockIdx.y * 32;
#pragma unroll
  for (int i = 0; i < 4; i++)
    tile[ty + i * 8][tx] = W[(size_t)(k0 + ty + i * 8) * Nd + n0 + tx];
  __syncthreads();
#pragma unroll
  for (int i = 0; i < 4; i++)
    WT[(size_t)(n0 + ty + i * 8) * Kd + k0 + tx] = f2bf(tile[tx][ty + i * 8]);
}

// -- transpose V from fused QKV: bf16 [B*T][QS] col 4096+ -> [B][E][T]
__global__ __launch_bounds__(256) void transpose_v_kernel(const u16* __restrict__ qkv,
                                                          u16* __restrict__ vt) {
  __shared__ u16 tile[32][33];
  int tx = threadIdx.x, ty = threadIdx.y;
  int b = blockIdx.z;
  int t0 = blockIdx.x * 32, e0 = blockIdx.y * 32;
#pragma unroll
  for (int i = 0; i < 4; i++)
    tile[ty + i * 8][tx] =
        qkv[(size_t)(b * T_SEQ + t0 + ty + i * 8) * QS + 2 * E_DIM + e0 + tx];
  __syncthreads();
#pragma unroll
  for (int i = 0; i < 4; i++)
    vt[((size_t)b * E_DIM + e0 + ty + i * 8) * T_SEQ + t0 + tx] = tile[tx][ty + i * 8];
}

// ======= GEMM BM_x256xBK64, 8-phase schedule, paired-row LDS ========
// Round-6 structure (best: 957us) with ONE change: 2-D XCD chunking.
// Each XCD's ~32 co-resident blocks form a CX x CY rectangle of the
// block grid, so both the A-panel and B-panel K-slices
// ((CX+CY)*32KB << 4MB L2) are fetched from L3 once per XCD and
// L2-served to CX (resp. CY) blocks -- the staging-bandwidth fix.
// bid = true dispatch id (y*gx+x); xcd = bid&7; slot = bid>>3;
// bx = (xcd%nchx)*CX + slot%CX; by = (xcd/nchx)*CY + slot/CX.
// Bijective whenever gridDim.x%CX==0, gridDim.y%CY==0 and
// (gx/CX)*(gy/CY)==8 (all our shapes).
// MODE 0: bf16 C.  MODE 1: Cout(f32)=Extra(f32)+acc.
// MODE 2: Cout(bf16)=silu(Extra bf16)*acc (Extra may alias Cout).
template <int MODE, int BM_>
__global__ __launch_bounds__(512, 1) void gemm8p(const u16* __restrict__ A,
                                                 const u16* __restrict__ BT,
                                                 void* __restrict__ Cout,
                                                 const void* __restrict__ Extra,
                                                 int N, int K, int CX, int CY) {
  constexpr int MM = BM_ / 64;
  constexpr int AUNIT = BM_ * 32;
  __shared__ u16 Abuf[4 * AUNIT];
  __shared__ u16 Bbuf[4 * 8192];
  const int t = threadIdx.x;
  const int w = t >> 6, l = t & 63, g = l >> 4, lq = l & 15;
  const int wm = w >> 2, wn = w & 3;

  // 2-D XCD chunk swizzle
  const int bid = blockIdx.y * gridDim.x + blockIdx.x;
  const int xcd = bid & 7, slot = bid >> 3;
  const int nchx = gridDim.x / CX;
  const int bx = (xcd % nchx) * CX + (slot % CX);
  const int by = (xcd / nchx) * CY + (slot / CX);
  const size_t bm = (size_t)by * BM_, bn = (size_t)bx * 256;

  // staging lane constants (paired-row): lane l covers
  // row = 2*(l>>3) + (l&1), kchunk = ((l>>1)&3) ^ ((l>>3)&3)
  const int srcrow = ((l >> 3) << 1) | (l & 1);
  const int csrc = ((((l >> 1) & 3) ^ ((l >> 3) & 3)) << 3);
  const u16* aSrc = A + (bm + w * 16 + srcrow) * (size_t)K + csrc;
  const u16* bSrc = BT + (bn + w * 16 + srcrow) * (size_t)K + csrc;
  // read lane constant: ch7 = (lq&1) + 2*(g ^ ((lq>>1)&3))
  const int rdoff = (((lq & 1) + 2 * (g ^ ((lq >> 1) & 3))) << 3);

#define STA8(DB, KS, TILE)                                                    \
  {                                                                           \
    u16* Ad = Abuf + (DB) * (2 * AUNIT) + (KS)*AUNIT + w * 512;               \
    const u16* as_ = aSrc + (size_t)(TILE)*64 + (KS)*32;                      \
    async16(Ad, as_);                                                         \
    if constexpr (BM_ == 256) async16(Ad + 4096, as_ + (size_t)128 * K);      \
  }
#define STB8(DB, KS, TILE)                                                    \
  {                                                                           \
    u16* Bd = Bbuf + (DB)*16384 + (KS)*8192 + w * 512;                        \
    const u16* bs_ = bSrc + (size_t)(TILE)*64 + (KS)*32;                      \
    async16(Bd, bs_);                                                         \
    async16(Bd + 4096, bs_ + (size_t)128 * K);                                \
  }
#define RDA8(DB, KS, MH)                                                      \
  _Pragma("unroll") for (int mm = 0; mm < MM; ++mm)                           \
      af[mm] = *(const short8*)(Abuf + (DB) * (2 * AUNIT) + (KS)*AUNIT +      \
                                (wm * (BM_ / 4) + (MH) * (BM_ / 8) + mm * 8 + \
                                 (lq >> 1)) * 64 + rdoff);
#define RDB8(DB, KS)                                                          \
  _Pragma("unroll") for (int nn = 0; nn < 4; ++nn)                            \
      bf[nn] = *(const short8*)(Bbuf + (DB)*16384 + (KS)*8192 +               \
                                (wn * 32 + nn * 8 + (lq >> 1)) * 64 + rdoff);
#define MM168(MH)                                                             \
  _Pragma("unroll") for (int mm = 0; mm < MM; ++mm)                           \
      _Pragma("unroll") for (int nn = 0; nn < 4; ++nn)                        \
          acc[(MH)*MM + mm][nn] = __builtin_amdgcn_mfma_f32_16x16x32_bf16(    \
              af[mm], bf[nn], acc[(MH)*MM + mm][nn], 0, 0, 0);
#define SYNCA                                                                 \
  __builtin_amdgcn_s_barrier();                                               \
  asm volatile("s_waitcnt lgkmcnt(0)" ::: "memory");                          \
  __builtin_amdgcn_sched_barrier(0);                                          \
  __builtin_amdgcn_s_setprio(1);
#define ENDP __builtin_amdgcn_s_setprio(0);
#define BAR2 __builtin_amdgcn_s_barrier();
#define WAITN                                                                 \
  if constexpr (BM_ == 256) asm volatile("s_waitcnt vmcnt(8)" ::: "memory");  \
  else                      asm volatile("s_waitcnt vmcnt(6)" ::: "memory");
#define WAITH                                                                 \
  if constexpr (BM_ == 256) asm volatile("s_waitcnt vmcnt(4)" ::: "memory");  \
  else                      asm volatile("s_waitcnt vmcnt(3)" ::: "memory");

  const int NT = K >> 6, NI = NT >> 1;
  f32x4 acc[2 * MM][4] = {};
  short8 af[MM > 4 ? MM : 4], bf[4];

  // prologue: tile0 both K-halves + tile1 K-half0
  STA8(0, 0, 0); STB8(0, 0, 0);
  STA8(0, 1, 0); STB8(0, 1, 0);
  STA8(1, 0, 1); STB8(1, 0, 1);
  WAITN;  // completes t0-ks0; rest stays in flight
  BAR2;

  for (int j = 0; j < NI; ++j) {
    const int t1 = 2 * j + 1, t2 = 2 * j + 2, t3 = 2 * j + 3;
    const bool s2 = t2 < NT, s3 = t3 < NT, lastI = (j + 1 == NI);
    // p0: db0 ks0 mh0
    RDB8(0, 0); RDA8(0, 0, 0);
    STA8(1, 1, t1);
    SYNCA; MM168(0); ENDP; BAR2;
    // p1: db0 ks0 mh1   (wait guards p2's db0ks1, staged p4',p5')
    RDA8(0, 0, 1);
    STB8(1, 1, t1);
    SYNCA; MM168(1); ENDP;
    WAITN;
    BAR2;
    // p2: db0 ks1 mh0
    RDB8(0, 1); RDA8(0, 1, 0);
    if (s2) STA8(0, 0, t2);
    SYNCA; MM168(0); ENDP; BAR2;
    // p3: db0 ks1 mh1   (wait guards p4's db1ks0, staged p6',p7')
    RDA8(0, 1, 1);
    if (s2) STB8(0, 0, t2);
    SYNCA; MM168(1); ENDP;
    if (lastI) { WAITH; } else { WAITN; }
    BAR2;
    // p4: db1 ks0 mh0
    RDB8(1, 0); RDA8(1, 0, 0);
    if (s2) STA8(0, 1, t2);
    SYNCA; MM168(0); ENDP; BAR2;
    // p5: db1 ks0 mh1   (wait guards p6's db1ks1, staged p0,p1)
    RDA8(1, 0, 1);
    if (s2) STB8(0, 1, t2);
    SYNCA; MM168(1); ENDP;
    if (lastI) { asm volatile("s_waitcnt vmcnt(0)" ::: "memory"); } else { WAITN; }
    BAR2;
    // p6: db1 ks1 mh0
    RDB8(1, 1); RDA8(1, 1, 0);
    if (s3) STA8(1, 0, t3);
    SYNCA; MM168(0); ENDP; BAR2;
    // p7: db1 ks1 mh1   (wait guards next p0's db0ks0, staged p2,p3)
    RDA8(1, 1, 1);
    if (s3) STB8(1, 0, t3);
    SYNCA; MM168(1); ENDP;
    if (!lastI) { WAITN; }
    BAR2;
  }
#undef STA8
#undef STB8
#undef RDA8
#undef RDB8
#undef MM168
#undef SYNCA
#undef ENDP
#undef BAR2
#undef WAITN
#undef WAITH

#pragma unroll
  for (int m = 0; m < 2 * MM; m++) {
    size_t row = bm + wm * (BM_ / 2) + m * 16 + 4 * g;
#pragma unroll
    for (int n = 0; n < 4; n++) {
      size_t col = bn + wn * 64 + n * 16 + lq;
#pragma unroll
      for (int r = 0; r < 4; r++) {
        size_t idx = (row + r) * (size_t)N + col;
        if constexpr (MODE == 0) {
          ((u16*)Cout)[idx] = f2bf(acc[m][n][r]);
        } else if constexpr (MODE == 1) {
          ((float*)Cout)[idx] = ((const float*)Extra)[idx] + acc[m][n][r];
        } else {
          float a = bf2f(((const u16*)Extra)[idx]);
          float sil = a / (1.f + exp2f(-1.4426950408889634f * a));
          ((u16*)Cout)[idx] = f2bf(sil * acc[m][n][r]);
        }
      }
    }
  }
}

// ----------------- causal flash attention (LDS-staged) --------------
// grid (T/64, B*H); 4 waves/block; block owns 64 q-rows of one (b,h);
// wave w owns rows q0blk + 16w .. +16.  KV tile = 64.
__global__ __launch_bounds__(256, 3) void attn_kernel(const u16* __restrict__ QKV,
                                                      const u16* __restrict__ VT,
                                                      u16* __restrict__ CTX) {
  __shared__ u16 Ks[64 * 128];
  __shared__ u16 Vs[128 * 64];
  __shared__ u16 P_all[4][16 * 72];
  const int t = threadIdx.x;
  const int w = t >> 6, l = t & 63, g = l >> 4, lq = l & 15;
  u16* P = P_all[w];
  const int q0blk = blockIdx.x * 64;
  const int q0w = q0blk + w * 16;
  const int bh = blockIdx.y, b = bh >> 4, h = bh & 15;
  const u16* qp = QKV + (size_t)b * T_SEQ * QS + h * D_HEAD;
  const u16* kp = QKV + (size_t)b * T_SEQ * QS + E_DIM + h * D_HEAD;
  const u16* vp = VT + ((size_t)b * E_DIM + h * D_HEAD) * T_SEQ;

  short8 qf[4];
#pragma unroll
  for (int ks = 0; ks < 4; ks++)
    qf[ks] = *(const short8*)(qp + (size_t)(q0w + lq) * QS + ks * 32 + g * 8);

  f32x4 acc[8] = {};
  float m2[4], ls[4];
#pragma unroll
  for (int r = 0; r < 4; r++) { m2[r] = -1e30f; ls[r] = 0.f; }
  const float sc = 0.08838834764831845f * 1.4426950408889634f;

  const int kRow0 = 16 * w + (l >> 4);
  const int kChunk = l & 15;
  const int vRow0 = 32 * w + (l >> 3);
  const int vChunk = l & 7;

  for (int kv0 = 0; kv0 <= q0blk; kv0 += 64) {
#pragma unroll
    for (int j = 0; j < 4; j++) {
      int R = kRow0 + 4 * j;
      async16(Ks + (16 * w + 4 * j) * 128,
              kp + (size_t)(kv0 + R) * QS + ((kChunk ^ (R & 7)) << 3));
    }
#pragma unroll
    for (int j = 0; j < 4; j++) {
      int D = vRow0 + 8 * j;
      async16(Vs + (32 * w + 8 * j) * 64,
              vp + (size_t)D * T_SEQ + kv0 + ((vChunk ^ (D & 7)) << 3));
    }
    __syncthreads();

    f32x4 s[4];
#pragma unroll
    for (int ct = 0; ct < 4; ct++) {
      s[ct] = f32x4{0.f, 0.f, 0.f, 0.f};
#pragma unroll
      for (int ks = 0; ks < 4; ks++) {
        short8 kf = *(const short8*)(Ks + (ct * 16 + lq) * 128 +
                                     (((ks * 4 + g) ^ (lq & 7)) << 3));
        s[ct] = __builtin_amdgcn_mfma_f32_16x16x32_bf16(qf[ks], kf, s[ct], 0, 0, 0);
      }
    }
    float sv[4][4];
#pragma unroll
    for (int ct = 0; ct < 4; ct++)
#pragma unroll
      for (int r = 0; r < 4; r++) sv[ct][r] = s[ct][r] * sc;
    if (kv0 + 64 > q0w) {
#pragma unroll
      for (int ct = 0; ct < 4; ct++)
#pragma unroll
        for (int r = 0; r < 4; r++)
          if (kv0 + ct * 16 + lq > q0w + 4 * g + r) sv[ct][r] = -1e30f;
    }
    float mx[4];
#pragma unroll
    for (int r = 0; r < 4; r++)
      mx[r] = fmaxf(fmaxf(sv[0][r], sv[1][r]), fmaxf(sv[2][r], sv[3][r]));
#pragma unroll
    for (int off = 1; off < 16; off <<= 1)
#pragma unroll
      for (int r = 0; r < 4; r++) mx[r] = fmaxf(mx[r], __shfl_xor(mx[r], off));
#pragma unroll
    for (int r = 0; r < 4; r++) {
      float mn = fmaxf(m2[r], mx[r]);
      float sca = exp2f(m2[r] - mn);
      m2[r] = mn;
      float sum = 0.f;
#pragma unroll
      for (int ct = 0; ct < 4; ct++) {
        float pv = exp2f(sv[ct][r] - mn);
        sum += pv;
        P[(4 * g + r) * 72 + ct * 16 + lq] = f2bf(pv);
      }
      ls[r] = ls[r] * sca + sum;
#pragma unroll
      for (int n = 0; n < 8; n++) acc[n][r] *= sca;
    }
    short8 pa[2];
#pragma unroll
    for (int ks2 = 0; ks2 < 2; ks2++)
      pa[ks2] = *(const short8*)(P + lq * 72 + ks2 * 32 + g * 8);
#pragma unroll
    for (int n = 0; n < 8; n++)
#pragma unroll
      for (int ks2 = 0; ks2 < 2; ks2++) {
        short8 vf = *(const short8*)(Vs + (n * 16 + lq) * 64 +
                                     (((ks2 * 4 + g) ^ (lq & 7)) << 3));
        acc[n] = __builtin_amdgcn_mfma_f32_16x16x32_bf16(pa[ks2], vf, acc[n], 0, 0, 0);
      }
    __syncthreads();
  }

#pragma unroll
  for (int off = 1; off < 16; off <<= 1)
#pragma unroll
    for (int r = 0; r < 4; r++) ls[r] += __shfl_xor(ls[r], off);
  float inv[4];
#pragma unroll
  for (int r = 0; r < 4; r++) inv[r] = 1.f / ls[r];
  u16* cp = CTX + ((size_t)b * T_SEQ + q0w) * E_DIM + h * D_HEAD;
#pragma unroll
  for (int n = 0; n < 8; n++)
#pragma unroll
    for (int r = 0; r < 4; r++)
      cp[(size_t)(4 * g + r) * E_DIM + n * 16 + lq] = f2bf(acc[n][r] * inv[r]);
}

extern "C" void kernel_launch(void* const* d_in, const int* in_sizes, int n_in,
                              void* d_out, int out_size, void* d_ws, size_t ws_size,
                              hipStream_t stream) {
  (void)in_sizes; (void)n_in; (void)out_size; (void)ws_size;
  const float* x  = (const float*)d_in[0];
  const float* g1 = (const float*)d_in[1];
  const float* b1 = (const float*)d_in[2];
  const float* wq = (const float*)d_in[3];
  const float* wk = (const float*)d_in[4];
  const float* wv = (const float*)d_in[5];
  const float* wo = (const float*)d_in[6];
  const float* g2 = (const float*)d_in[7];
  const float* b2 = (const float*)d_in[8];
  const float* w1 = (const float*)d_in[9];
  const float* w2 = (const float*)d_in[10];
  const float* w3 = (const float*)d_in[11];
  float* out = (float*)d_out;

  const size_t EE2 = (size_t)E_DIM * E_DIM * 2;
  const size_t EF2 = (size_t)E_DIM * FFN_DIM * 2;
  const size_t ME2 = (size_t)M_ROWS * E_DIM * 2;
  char* p = (char*)d_ws;
  u16* wqkvT = (u16*)p; p += 3 * EE2;
  u16* woT = (u16*)p; p += EE2;
  u16* w1T = (u16*)p; p += EF2;
  u16* w2T = (u16*)p; p += EF2;
  u16* w3T = (u16*)p; p += EF2;
  u16* Hb  = (u16*)p; p += ME2;
  u16* QKVb = (u16*)p; p += (size_t)M_ROWS * QS * 2;
  u16* VTb = (u16*)p; p += ME2;
  u16* CTXb = (u16*)p; p += ME2;
  u16* U1b = QKVb;  // u1/gated reuses QKVb+VTb

  dim3 blk32(32, 8);
  cvt_t_kernel<<<dim3(E_DIM / 32, E_DIM / 32), blk32, 0, stream>>>(wq, wqkvT, E_DIM, E_DIM);
  cvt_t_kernel<<<dim3(E_DIM / 32, E_DIM / 32), blk32, 0, stream>>>(wk, wqkvT + E_DIM * E_DIM, E_DIM, E_DIM);
  cvt_t_kernel<<<dim3(E_DIM / 32, E_DIM / 32), blk32, 0, stream>>>(wv, wqkvT + 2 * E_DIM * E_DIM, E_DIM, E_DIM);
  cvt_t_kernel<<<dim3(E_DIM / 32, E_DIM / 32), blk32, 0, stream>>>(wo, woT, E_DIM, E_DIM);
  cvt_t_kernel<<<dim3(FFN_DIM / 32, E_DIM / 32), blk32, 0, stream>>>(w1, w1T, E_DIM, FFN_DIM);
  cvt_t_kernel<<<dim3(FFN_DIM / 32, E_DIM / 32), blk32, 0, stream>>>(w2, w2T, E_DIM, FFN_DIM);
  cvt_t_kernel<<<dim3(E_DIM / 32, FFN_DIM / 32), blk32, 0, stream>>>(w3, w3T, FFN_DIM, E_DIM);

  // attention block
  ln_kernel<<<M_ROWS, 256, 0, stream>>>(x, g1, b1, Hb);
  // fused QKV GEMM: grid (24,32); per-XCD chunk 6x16
  gemm8p<0, 128><<<dim3(QS / 256, M_ROWS / 128), 512, 0, stream>>>(Hb, wqkvT, QKVb, nullptr, QS, E_DIM, 6, 16);
  transpose_v_kernel<<<dim3(T_SEQ / 32, E_DIM / 32, 2), blk32, 0, stream>>>(QKVb, VTb);
  attn_kernel<<<dim3(T_SEQ / 64, 2 * N_HEAD), 256, 0, stream>>>(QKVb, VTb, CTXb);
  // WO: grid (8,32); per-XCD chunk 4x8
  gemm8p<1, 128><<<dim3(E_DIM / 256, M_ROWS / 128), 512, 0, stream>>>(CTXb, woT, out, x, E_DIM, E_DIM, 4, 8);

  // SwiGLU MLP block
  ln_kernel<<<M_ROWS, 256, 0, stream>>>(out, g2, b2, Hb);
  // FFN: grid (32,16); per-XCD chunk 8x8
  gemm8p<0, 256><<<dim3(FFN_DIM / 256, M_ROWS / 256), 512, 0, stream>>>(Hb, w1T, U1b, nullptr, FFN_DIM, E_DIM, 8, 8);
  gemm8p<2, 256><<<dim3(FFN_DIM / 256, M_ROWS / 256), 512, 0, stream>>>(Hb, w2T, U1b, U1b, FFN_DIM, E_DIM, 8, 8);
  // w3: grid (8,32); per-XCD chunk 4x8
  gemm8p<1, 128><<<dim3(E_DIM / 256, M_ROWS / 128), 512, 0, stream>>>(U1b, w3T, out, out, E_DIM, FFN_DIM, 4, 8);
}

// Round 11
// 910.191 us; speedup vs baseline: 1.0698x; 1.0353x over previous
//
#include <hip/hip_runtime.h>

// Transformer layer, bf16 MFMA compute, fp32 I/O.
// B=2 T=2048 E=2048 H=16 DH=128 FFN=8192. Needs ~256MB workspace.

#define T_SEQ 2048
#define E_DIM 2048
#define N_HEAD 16
#define D_HEAD 128
#define FFN_DIM 8192
#define M_ROWS 4096  // B*T
#define QS (3 * E_DIM)  // fused QKV row stride

typedef unsigned short u16;
typedef short short8 __attribute__((ext_vector_type(8)));
typedef float f32x4 __attribute__((ext_vector_type(4)));

#define DEV __device__ __forceinline__

DEV u16 f2bf(float f) {
  unsigned u = __float_as_uint(f);
  u += 0x7fffu + ((u >> 16) & 1u);
  return (u16)(u >> 16);
}
DEV float bf2f(u16 h) { return __uint_as_float(((unsigned)h) << 16); }

DEV void async16(void* lds, const void* g) {
  __builtin_amdgcn_global_load_lds((const __attribute__((address_space(1))) void*)g,
                                   (__attribute__((address_space(3))) void*)lds, 16, 0, 0);
}

// ---------------- LayerNorm: fp32 [rows][E] -> bf16 -----------------
__global__ __launch_bounds__(256) void ln_kernel(const float* __restrict__ x,
                                                 const float* __restrict__ gw,
                                                 const float* __restrict__ bw,
                                                 u16* __restrict__ out) {
  int row = blockIdx.x;
  int t = threadIdx.x;
  const float4* xr = (const float4*)(x + (size_t)row * E_DIM);
  float4 a = xr[t], c = xr[t + 256];
  float s = a.x + a.y + a.z + a.w + c.x + c.y + c.z + c.w;
  float q = a.x * a.x + a.y * a.y + a.z * a.z + a.w * a.w +
            c.x * c.x + c.y * c.y + c.z * c.z + c.w * c.w;
  for (int off = 32; off > 0; off >>= 1) {
    s += __shfl_down(s, off);
    q += __shfl_down(q, off);
  }
  __shared__ float red[8];
  if ((t & 63) == 0) { red[(t >> 6) * 2] = s; red[(t >> 6) * 2 + 1] = q; }
  __syncthreads();
  s = red[0] + red[2] + red[4] + red[6];
  q = red[1] + red[3] + red[5] + red[7];
  float mu = s * (1.f / E_DIM);
  float rs = rsqrtf(q * (1.f / E_DIM) - mu * mu + 1e-5f);
  const float4* g4 = (const float4*)gw;
  const float4* b4 = (const float4*)bw;
  float4 g0 = g4[t], g1v = g4[t + 256], e0 = b4[t], e1 = b4[t + 256];
  ushort4 o0, o1;
  o0.x = f2bf((a.x - mu) * rs * g0.x + e0.x);
  o0.y = f2bf((a.y - mu) * rs * g0.y + e0.y);
  o0.z = f2bf((a.z - mu) * rs * g0.z + e0.z);
  o0.w = f2bf((a.w - mu) * rs * g0.w + e0.w);
  o1.x = f2bf((c.x - mu) * rs * g1v.x + e1.x);
  o1.y = f2bf((c.y - mu) * rs * g1v.y + e1.y);
  o1.z = f2bf((c.z - mu) * rs * g1v.z + e1.z);
  o1.w = f2bf((c.w - mu) * rs * g1v.w + e1.w);
  ((ushort4*)(out + (size_t)row * E_DIM))[t] = o0;
  ((ushort4*)(out + (size_t)row * E_DIM))[t + 256] = o1;
}

// ------- convert+transpose: fp32 W[K][N] -> bf16 WT[N][K] -----------
__global__ __launch_bounds__(256) void cvt_t_kernel(const float* __restrict__ W,
                                                    u16* __restrict__ WT,
                                                    int Kd, int Nd) {
  __shared__ float tile[32][33];
  int tx = threadIdx.x, ty = threadIdx.y;
  int n0 = blockIdx.x * 32, k0 = blockIdx.y * 32;
#pragma unroll
  for (int i = 0; i < 4; i++)
    tile[ty + i * 8][tx] = W[(size_t)(k0 + ty + i * 8) * Nd + n0 + tx];
  __syncthreads();
#pragma unroll
  for (int i = 0; i < 4; i++)
    WT[(size_t)(n0 + ty + i * 8) * Kd + k0 + tx] = f2bf(tile[tx][ty + i * 8]);
}

// -- transpose V from fused QKV: bf16 [B*T][QS] col 4096+ -> [B][E][T]
__global__ __launch_bounds__(256) void transpose_v_kernel(const u16* __restrict__ qkv,
                                                          u16* __restrict__ vt) {
  __shared__ u16 tile[32][33];
  int tx = threadIdx.x, ty = threadIdx.y;
  int b = blockIdx.z;
  int t0 = blockIdx.x * 32, e0 = blockIdx.y * 32;
#pragma unroll
  for (int i = 0; i < 4; i++)
    tile[ty + i * 8][tx] =
        qkv[(size_t)(b * T_SEQ + t0 + ty + i * 8) * QS + 2 * E_DIM + e0 + tx];
  __syncthreads();
#pragma unroll
  for (int i = 0; i < 4; i++)
    vt[((size_t)b * E_DIM + e0 + ty + i * 8) * T_SEQ + t0 + tx] = tile[tx][ty + i * 8];
}

// ------------- add3: out += P0 + P1 (split-K reduction) -------------
__global__ __launch_bounds__(256) void add3_kernel(float* __restrict__ out,
                                                   const float* __restrict__ pk) {
  const size_t MN4 = (size_t)M_ROWS * E_DIM / 4;  // in float4
  size_t i = (size_t)blockIdx.x * 256 + threadIdx.x;
  const float4* p04 = (const float4*)pk;
  const float4* p14 = (const float4*)(pk + (size_t)M_ROWS * E_DIM);
  float4* o4 = (float4*)out;
#pragma unroll
  for (int k = 0; k < 4; k++) {
    size_t idx = i + (size_t)k * 524288;  // 2048 blk * 256 thr
    if (idx < MN4) {
      float4 o = o4[idx], a = p04[idx], b = p14[idx];
      o.x += a.x + b.x; o.y += a.y + b.y;
      o.z += a.z + b.z; o.w += a.w + b.w;
      o4[idx] = o;
    }
  }
}

// ======= GEMM BM_x256xBK64, 8-phase schedule, paired-row LDS ========
// Round-9 structure + split-K support: gridDim.z = K-splits; kz is
// derived from the XCD swizzle (nchx*nchy*gridDim.z must == 8), so
// each XCD's 32 blocks form a CXxCY rectangle at one kz.  A/B row
// strides are lda/ldb (full K); the K loop covers [kz*K, kz*K+K).
// MODE 0: bf16 C.  MODE 1: Cout(f32)=Extra(f32)+acc.
// MODE 2: Cout(bf16)=silu(Extra bf16)*acc.
// MODE 3: Cout(f32 partial) at Cout + kz*M*N (split-K partials).
template <int MODE, int BM_>
__global__ __launch_bounds__(512, 1) void gemm8p(const u16* __restrict__ A,
                                                 const u16* __restrict__ BT,
                                                 void* __restrict__ Cout,
                                                 const void* __restrict__ Extra,
                                                 int N, int K, int lda, int ldb,
                                                 int CX, int CY) {
  constexpr int MM = BM_ / 64;
  constexpr int AUNIT = BM_ * 32;
  __shared__ u16 Abuf[4 * AUNIT];
  __shared__ u16 Bbuf[4 * 8192];
  const int t = threadIdx.x;
  const int w = t >> 6, l = t & 63, g = l >> 4, lq = l & 15;
  const int wm = w >> 2, wn = w & 3;

  // 2-D XCD chunk swizzle (+ kz from chunk id)
  const int bid = (blockIdx.z * gridDim.y + blockIdx.y) * gridDim.x + blockIdx.x;
  const int xcd = bid & 7, slot = bid >> 3;
  const int nchx = gridDim.x / CX;
  const int nchy = gridDim.y / CY;
  const int cpz = nchx * nchy;
  const int kz = xcd / cpz;
  const int cid = xcd % cpz;
  const int bx = (cid % nchx) * CX + (slot % CX);
  const int by = (cid / nchx) * CY + (slot / CX);
  const size_t bm = (size_t)by * BM_, bn = (size_t)bx * 256;
  const size_t koff = (size_t)kz * K;

  // staging lane constants (paired-row): lane l covers
  // row = 2*(l>>3) + (l&1), kchunk = ((l>>1)&3) ^ ((l>>3)&3)
  const int srcrow = ((l >> 3) << 1) | (l & 1);
  const int csrc = ((((l >> 1) & 3) ^ ((l >> 3) & 3)) << 3);
  const u16* aSrc = A + (bm + w * 16 + srcrow) * (size_t)lda + koff + csrc;
  const u16* bSrc = BT + (bn + w * 16 + srcrow) * (size_t)ldb + koff + csrc;
  // read lane constant: ch7 = (lq&1) + 2*(g ^ ((lq>>1)&3))
  const int rdoff = (((lq & 1) + 2 * (g ^ ((lq >> 1) & 3))) << 3);

#define STA8(DB, KS, TILE)                                                    \
  {                                                                           \
    u16* Ad = Abuf + (DB) * (2 * AUNIT) + (KS)*AUNIT + w * 512;               \
    const u16* as_ = aSrc + (size_t)(TILE)*64 + (KS)*32;                      \
    async16(Ad, as_);                                                         \
    if constexpr (BM_ == 256) async16(Ad + 4096, as_ + (size_t)128 * lda);    \
  }
#define STB8(DB, KS, TILE)                                                    \
  {                                                                           \
    u16* Bd = Bbuf + (DB)*16384 + (KS)*8192 + w * 512;                        \
    const u16* bs_ = bSrc + (size_t)(TILE)*64 + (KS)*32;                      \
    async16(Bd, bs_);                                                         \
    async16(Bd + 4096, bs_ + (size_t)128 * ldb);                              \
  }
#define RDA8(DB, KS, MH)                                                      \
  _Pragma("unroll") for (int mm = 0; mm < MM; ++mm)                           \
      af[mm] = *(const short8*)(Abuf + (DB) * (2 * AUNIT) + (KS)*AUNIT +      \
                                (wm * (BM_ / 4) + (MH) * (BM_ / 8) + mm * 8 + \
                                 (lq >> 1)) * 64 + rdoff);
#define RDB8(DB, KS)                                                          \
  _Pragma("unroll") for (int nn = 0; nn < 4; ++nn)                            \
      bf[nn] = *(const short8*)(Bbuf + (DB)*16384 + (KS)*8192 +               \
                                (wn * 32 + nn * 8 + (lq >> 1)) * 64 + rdoff);
#define MM168(MH)                                                             \
  _Pragma("unroll") for (int mm = 0; mm < MM; ++mm)                           \
      _Pragma("unroll") for (int nn = 0; nn < 4; ++nn)                        \
          acc[(MH)*MM + mm][nn] = __builtin_amdgcn_mfma_f32_16x16x32_bf16(    \
              af[mm], bf[nn], acc[(MH)*MM + mm][nn], 0, 0, 0);
#define SYNCA                                                                 \
  __builtin_amdgcn_s_barrier();                                               \
  asm volatile("s_waitcnt lgkmcnt(0)" ::: "memory");                          \
  __builtin_amdgcn_sched_barrier(0);                                          \
  __builtin_amdgcn_s_setprio(1);
#define ENDP __builtin_amdgcn_s_setprio(0);
#define BAR2 __builtin_amdgcn_s_barrier();
#define WAITN                                                                 \
  if constexpr (BM_ == 256) asm volatile("s_waitcnt vmcnt(8)" ::: "memory");  \
  else                      asm volatile("s_waitcnt vmcnt(6)" ::: "memory");
#define WAITH                                                                 \
  if constexpr (BM_ == 256) asm volatile("s_waitcnt vmcnt(4)" ::: "memory");  \
  else                      asm volatile("s_waitcnt vmcnt(3)" ::: "memory");

  const int NT = K >> 6, NI = NT >> 1;
  f32x4 acc[2 * MM][4] = {};
  short8 af[MM > 4 ? MM : 4], bf[4];

  // prologue: tile0 both K-halves + tile1 K-half0
  STA8(0, 0, 0); STB8(0, 0, 0);
  STA8(0, 1, 0); STB8(0, 1, 0);
  STA8(1, 0, 1); STB8(1, 0, 1);
  WAITN;  // completes t0-ks0; rest stays in flight
  BAR2;

  for (int j = 0; j < NI; ++j) {
    const int t1 = 2 * j + 1, t2 = 2 * j + 2, t3 = 2 * j + 3;
    const bool s2 = t2 < NT, s3 = t3 < NT, lastI = (j + 1 == NI);
    // p0: db0 ks0 mh0
    RDB8(0, 0); RDA8(0, 0, 0);
    STA8(1, 1, t1);
    SYNCA; MM168(0); ENDP; BAR2;
    // p1: db0 ks0 mh1
    RDA8(0, 0, 1);
    STB8(1, 1, t1);
    SYNCA; MM168(1); ENDP;
    WAITN;
    BAR2;
    // p2: db0 ks1 mh0
    RDB8(0, 1); RDA8(0, 1, 0);
    if (s2) STA8(0, 0, t2);
    SYNCA; MM168(0); ENDP; BAR2;
    // p3: db0 ks1 mh1
    RDA8(0, 1, 1);
    if (s2) STB8(0, 0, t2);
    SYNCA; MM168(1); ENDP;
    if (lastI) { WAITH; } else { WAITN; }
    BAR2;
    // p4: db1 ks0 mh0
    RDB8(1, 0); RDA8(1, 0, 0);
    if (s2) STA8(0, 1, t2);
    SYNCA; MM168(0); ENDP; BAR2;
    // p5: db1 ks0 mh1
    RDA8(1, 0, 1);
    if (s2) STB8(0, 1, t2);
    SYNCA; MM168(1); ENDP;
    if (lastI) { asm volatile("s_waitcnt vmcnt(0)" ::: "memory"); } else { WAITN; }
    BAR2;
    // p6: db1 ks1 mh0
    RDB8(1, 1); RDA8(1, 1, 0);
    if (s3) STA8(1, 0, t3);
    SYNCA; MM168(0); ENDP; BAR2;
    // p7: db1 ks1 mh1
    RDA8(1, 1, 1);
    if (s3) STB8(1, 0, t3);
    SYNCA; MM168(1); ENDP;
    if (!lastI) { WAITN; }
    BAR2;
  }
#undef STA8
#undef STB8
#undef RDA8
#undef RDB8
#undef MM168
#undef SYNCA
#undef ENDP
#undef BAR2
#undef WAITN
#undef WAITH

  const size_t mn = (size_t)gridDim.y * BM_ * (size_t)N;
#pragma unroll
  for (int m = 0; m < 2 * MM; m++) {
    size_t row = bm + wm * (BM_ / 2) + m * 16 + 4 * g;
#pragma unroll
    for (int n = 0; n < 4; n++) {
      size_t col = bn + wn * 64 + n * 16 + lq;
#pragma unroll
      for (int r = 0; r < 4; r++) {
        size_t idx = (row + r) * (size_t)N + col;
        if constexpr (MODE == 0) {
          ((u16*)Cout)[idx] = f2bf(acc[m][n][r]);
        } else if constexpr (MODE == 1) {
          ((float*)Cout)[idx] = ((const float*)Extra)[idx] + acc[m][n][r];
        } else if constexpr (MODE == 2) {
          float a = bf2f(((const u16*)Extra)[idx]);
          float sil = a / (1.f + exp2f(-1.4426950408889634f * a));
          ((u16*)Cout)[idx] = f2bf(sil * acc[m][n][r]);
        } else {
          ((float*)Cout)[(size_t)kz * mn + idx] = acc[m][n][r];
        }
      }
    }
  }
}

// ----------------- causal flash attention (LDS-staged) --------------
// grid (T/128, B*H); 4 waves/block; block owns 128 q-rows of one
// (b,h); wave w owns rows q0blk+32w .. +32 (2 row-groups of 16).
// KV tile = 64 staged once per block per iter -> staging/barriers per
// q-row halved vs QBLK16.  Wave-uniform skip of fully-masked rgs.
__global__ __launch_bounds__(256, 2) void attn_kernel(const u16* __restrict__ QKV,
                                                      const u16* __restrict__ VT,
                                                      u16* __restrict__ CTX) {
  __shared__ u16 Ks[64 * 128];       // 16 KB
  __shared__ u16 Vs[128 * 64];       // 16 KB
  __shared__ u16 P_all[4][32 * 72];  // 18 KB
  const int t = threadIdx.x;
  const int w = t >> 6, l = t & 63, g = l >> 4, lq = l & 15;
  u16* P = P_all[w];
  const int q0blk = blockIdx.x * 128;
  const int q0w = q0blk + w * 32;
  const int bh = blockIdx.y, b = bh >> 4, h = bh & 15;
  const u16* qp = QKV + (size_t)b * T_SEQ * QS + h * D_HEAD;
  const u16* kp = QKV + (size_t)b * T_SEQ * QS + E_DIM + h * D_HEAD;
  const u16* vp = VT + ((size_t)b * E_DIM + h * D_HEAD) * T_SEQ;

  short8 qf[2][4];
#pragma unroll
  for (int rg = 0; rg < 2; rg++)
#pragma unroll
    for (int ks = 0; ks < 4; ks++)
      qf[rg][ks] =
          *(const short8*)(qp + (size_t)(q0w + rg * 16 + lq) * QS + ks * 32 + g * 8);

  f32x4 acc[2][8] = {};
  float m2[2][4], ls[2][4];
#pragma unroll
  for (int rg = 0; rg < 2; rg++)
#pragma unroll
    for (int r = 0; r < 4; r++) { m2[rg][r] = -1e30f; ls[rg][r] = 0.f; }
  const float sc = 0.08838834764831845f * 1.4426950408889634f;  // 1/sqrt(128)*log2e

  const int kRow0 = 16 * w + (l >> 4);
  const int kChunk = l & 15;
  const int vRow0 = 32 * w + (l >> 3);
  const int vChunk = l & 7;

  for (int kv0 = 0; kv0 < q0blk + 128; kv0 += 64) {
#pragma unroll
    for (int j = 0; j < 4; j++) {
      int R = kRow0 + 4 * j;
      async16(Ks + (16 * w + 4 * j) * 128,
              kp + (size_t)(kv0 + R) * QS + ((kChunk ^ (R & 7)) << 3));
    }
#pragma unroll
    for (int j = 0; j < 4; j++) {
      int D = vRow0 + 8 * j;
      async16(Vs + (32 * w + 8 * j) * 64,
              vp + (size_t)D * T_SEQ + kv0 + ((vChunk ^ (D & 7)) << 3));
    }
    __syncthreads();

#pragma unroll
    for (int rg = 0; rg < 2; rg++) {
      const int rb = q0w + rg * 16;           // row base of this group
      if (kv0 > rb + 15) continue;            // fully masked (wave-uniform)
      f32x4 s[4];
      __builtin_amdgcn_s_setprio(1);
#pragma unroll
      for (int ct = 0; ct < 4; ct++) {
        s[ct] = f32x4{0.f, 0.f, 0.f, 0.f};
#pragma unroll
        for (int ks = 0; ks < 4; ks++) {
          short8 kf = *(const short8*)(Ks + (ct * 16 + lq) * 128 +
                                       (((ks * 4 + g) ^ (lq & 7)) << 3));
          s[ct] = __builtin_amdgcn_mfma_f32_16x16x32_bf16(qf[rg][ks], kf, s[ct], 0, 0, 0);
        }
      }
      __builtin_amdgcn_s_setprio(0);
      float sv[4][4];
#pragma unroll
      for (int ct = 0; ct < 4; ct++)
#pragma unroll
        for (int r = 0; r < 4; r++) sv[ct][r] = s[ct][r] * sc;
      if (kv0 + 64 > rb) {  // tile touches the diagonal for this rg
#pragma unroll
        for (int ct = 0; ct < 4; ct++)
#pragma unroll
          for (int r = 0; r < 4; r++)
            if (kv0 + ct * 16 + lq > rb + 4 * g + r) sv[ct][r] = -1e30f;
      }
      float mx[4];
#pragma unroll
      for (int r = 0; r < 4; r++)
        mx[r] = fmaxf(fmaxf(sv[0][r], sv[1][r]), fmaxf(sv[2][r], sv[3][r]));
#pragma unroll
      for (int off = 1; off < 16; off <<= 1)
#pragma unroll
        for (int r = 0; r < 4; r++) mx[r] = fmaxf(mx[r], __shfl_xor(mx[r], off));
#pragma unroll
      for (int r = 0; r < 4; r++) {
        float mn = fmaxf(m2[rg][r], mx[r]);
        float sca = exp2f(m2[rg][r] - mn);
        m2[rg][r] = mn;
        float sum = 0.f;
#pragma unroll
        for (int ct = 0; ct < 4; ct++) {
          float pv = exp2f(sv[ct][r] - mn);
          sum += pv;
          P[(rg * 16 + 4 * g + r) * 72 + ct * 16 + lq] = f2bf(pv);
        }
        ls[rg][r] = ls[rg][r] * sca + sum;
#pragma unroll
        for (int n = 0; n < 8; n++) acc[rg][n][r] *= sca;
      }
      short8 pa[2];
#pragma unroll
      for (int ks2 = 0; ks2 < 2; ks2++)
        pa[ks2] = *(const short8*)(P + (rg * 16 + lq) * 72 + ks2 * 32 + g * 8);
      __builtin_amdgcn_s_setprio(1);
#pragma unroll
      for (int n = 0; n < 8; n++)
#pragma unroll
        for (int ks2 = 0; ks2 < 2; ks2++) {
          short8 vf = *(const short8*)(Vs + (n * 16 + lq) * 64 +
                                       (((ks2 * 4 + g) ^ (lq & 7)) << 3));
          acc[rg][n] = __builtin_amdgcn_mfma_f32_16x16x32_bf16(pa[ks2], vf, acc[rg][n], 0, 0, 0);
        }
      __builtin_amdgcn_s_setprio(0);
    }
    __syncthreads();
  }

#pragma unroll
  for (int rg = 0; rg < 2; rg++) {
#pragma unroll
    for (int off = 1; off < 16; off <<= 1)
#pragma unroll
      for (int r = 0; r < 4; r++) ls[rg][r] += __shfl_xor(ls[rg][r], off);
  }
  u16* cp = CTX + ((size_t)b * T_SEQ + q0w) * E_DIM + h * D_HEAD;
#pragma unroll
  for (int rg = 0; rg < 2; rg++) {
    float inv[4];
#pragma unroll
    for (int r = 0; r < 4; r++) inv[r] = 1.f / ls[rg][r];
#pragma unroll
    for (int n = 0; n < 8; n++)
#pragma unroll
      for (int r = 0; r < 4; r++)
        cp[(size_t)(rg * 16 + 4 * g + r) * E_DIM + n * 16 + lq] =
            f2bf(acc[rg][n][r] * inv[r]);
  }
}

extern "C" void kernel_launch(void* const* d_in, const int* in_sizes, int n_in,
                              void* d_out, int out_size, void* d_ws, size_t ws_size,
                              hipStream_t stream) {
  (void)in_sizes; (void)n_in; (void)out_size; (void)ws_size;
  const float* x  = (const float*)d_in[0];
  const float* g1 = (const float*)d_in[1];
  const float* b1 = (const float*)d_in[2];
  const float* wq = (const float*)d_in[3];
  const float* wk = (const float*)d_in[4];
  const float* wv = (const float*)d_in[5];
  const float* wo = (const float*)d_in[6];
  const float* g2 = (const float*)d_in[7];
  const float* b2 = (const float*)d_in[8];
  const float* w1 = (const float*)d_in[9];
  const float* w2 = (const float*)d_in[10];
  const float* w3 = (const float*)d_in[11];
  float* out = (float*)d_out;

  const size_t EE2 = (size_t)E_DIM * E_DIM * 2;
  const size_t EF2 = (size_t)E_DIM * FFN_DIM * 2;
  const size_t ME2 = (size_t)M_ROWS * E_DIM * 2;
  char* p = (char*)d_ws;
  u16* wqkvT = (u16*)p; p += 3 * EE2;
  u16* woT = (u16*)p; p += EE2;
  u16* w1T = (u16*)p; p += EF2;
  u16* w2T = (u16*)p; p += EF2;
  u16* w3T = (u16*)p; p += EF2;
  u16* Hb  = (u16*)p; p += ME2;
  u16* QKVb = (u16*)p; p += (size_t)M_ROWS * QS * 2;
  u16* VTb = (u16*)p; p += ME2;
  u16* CTXb = (u16*)p; p += ME2;
  u16* U1b = QKVb;              // u1/gated reuses QKVb+VTb (64MB)
  float* Pk = (float*)wqkvT;    // w3 split-K partials: 64MB over
                                // wqkvT(48)+woT(16), both dead by w3

  dim3 blk32(32, 8);
  cvt_t_kernel<<<dim3(E_DIM / 32, E_DIM / 32), blk32, 0, stream>>>(wq, wqkvT, E_DIM, E_DIM);
  cvt_t_kernel<<<dim3(E_DIM / 32, E_DIM / 32), blk32, 0, stream>>>(wk, wqkvT + E_DIM * E_DIM, E_DIM, E_DIM);
  cvt_t_kernel<<<dim3(E_DIM / 32, E_DIM / 32), blk32, 0, stream>>>(wv, wqkvT + 2 * E_DIM * E_DIM, E_DIM, E_DIM);
  cvt_t_kernel<<<dim3(E_DIM / 32, E_DIM / 32), blk32, 0, stream>>>(wo, woT, E_DIM, E_DIM);
  cvt_t_kernel<<<dim3(FFN_DIM / 32, E_DIM / 32), blk32, 0, stream>>>(w1, w1T, E_DIM, FFN_DIM);
  cvt_t_kernel<<<dim3(FFN_DIM / 32, E_DIM / 32), blk32, 0, stream>>>(w2, w2T, E_DIM, FFN_DIM);
  cvt_t_kernel<<<dim3(E_DIM / 32, FFN_DIM / 32), blk32, 0, stream>>>(w3, w3T, FFN_DIM, E_DIM);

  // attention block
  ln_kernel<<<M_ROWS, 256, 0, stream>>>(x, g1, b1, Hb);
  // fused QKV GEMM: grid (24,32); per-XCD chunk 6x16
  gemm8p<0, 128><<<dim3(QS / 256, M_ROWS / 128), 512, 0, stream>>>(
      Hb, wqkvT, QKVb, nullptr, QS, E_DIM, E_DIM, E_DIM, 6, 16);
  transpose_v_kernel<<<dim3(T_SEQ / 32, E_DIM / 32, 2), blk32, 0, stream>>>(QKVb, VTb);
  attn_kernel<<<dim3(T_SEQ / 128, 2 * N_HEAD), 256, 0, stream>>>(QKVb, VTb, CTXb);
  // WO: grid (8,32); per-XCD chunk 4x8
  gemm8p<1, 128><<<dim3(E_DIM / 256, M_ROWS / 128), 512, 0, stream>>>(
      CTXb, woT, out, x, E_DIM, E_DIM, E_DIM, E_DIM, 4, 8);

  // SwiGLU MLP block
  ln_kernel<<<M_ROWS, 256, 0, stream>>>(out, g2, b2, Hb);
  // FFN: grid (32,16) BM256; per-XCD chunk 8x8
  gemm8p<0, 256><<<dim3(FFN_DIM / 256, M_ROWS / 256), 512, 0, stream>>>(
      Hb, w1T, U1b, nullptr, FFN_DIM, E_DIM, E_DIM, E_DIM, 8, 8);
  gemm8p<2, 256><<<dim3(FFN_DIM / 256, M_ROWS / 256), 512, 0, stream>>>(
      Hb, w2T, U1b, U1b, FFN_DIM, E_DIM, E_DIM, E_DIM, 8, 8);
  // w3: BM256 split-K=2: grid (8,16,2) = 256 blocks full chip;
  // per-XCD chunk 4x8 at one kz (nchx*nchy*gz = 2*2*2 = 8)
  gemm8p<3, 256><<<dim3(E_DIM / 256, M_ROWS / 256, 2), 512, 0, stream>>>(
      U1b, w3T, Pk, nullptr, E_DIM, FFN_DIM / 2, FFN_DIM, FFN_DIM, 4, 8);
  add3_kernel<<<2048, 256, 0, stream>>>(out, Pk);
}